// Round 10
// baseline (399.141 us; speedup 1.0000x reference)
//
#include <hip/hip_runtime.h>
#include <hip/hip_bf16.h>
#include <math.h>

// GCN. CSR via block-privatized 2-pass counting sort (single-writer lines).
// r10: non-temporal loads/stores on every single-use stream (eidx, t1, logits,
// wraw) so the gathered arrays (xbf 12.8MB, z2 6.4MB) keep per-XCD L2
// residency (r9: FETCH=70MB vs z2=6.4MB -> 35% hit rate, polluted by own
// streams). logits stored bf16. __launch_bounds__(256,4) frees VGPRs for the
// hoisted gather burst (r9 VGPR=36 strangled MLP).

#define F 64
#define OUTF 32
#define PB 128            // edge-partition blocks (privatized sort)
#define LEDGE 5632        // per-bucket LDS capacity (mean 4096)
#define BN_INV 0.9999950000374997f  // rsqrt(1 + 1e-5)

__device__ __forceinline__ unsigned fenc(float f) {
    unsigned u = __float_as_uint(f);
    return (u & 0x80000000u) ? ~u : (u | 0x80000000u);
}
__device__ __forceinline__ float fdec(unsigned e) {
    return (e & 0x80000000u) ? __uint_as_float(e & 0x7fffffffu) : __uint_as_float(~e);
}
__device__ __forceinline__ unsigned short f2bf(float f) {  // RNE
    unsigned u = __float_as_uint(f);
    return (unsigned short)((u + 0x7fffu + ((u >> 16) & 1u)) >> 16);
}
__device__ __forceinline__ float bf2f(unsigned short h) {
    return __uint_as_float((unsigned)h << 16);
}
__device__ __forceinline__ unsigned long long us4_u64(ushort4 v) {
    return (unsigned long long)v.x | ((unsigned long long)v.y << 16) |
           ((unsigned long long)v.z << 32) | ((unsigned long long)v.w << 48);
}

// red layout: [0..31] acc_c, [32] esum, [33] min-enc(uint), [34] max-enc(uint)

__global__ void k_fuse(const float* __restrict__ W2, const float* __restrict__ b2,
                       const float* __restrict__ l2w, const float* __restrict__ l2b,
                       float* __restrict__ w2l2, float* __restrict__ b2l2, float* __restrict__ red) {
    int t = blockIdx.x * blockDim.x + threadIdx.x;  // 2048 threads
    int k = t >> 5, cc = t & 31;
    float o = 0.0f;
    for (int j = 0; j < F; j++) o += W2[k * F + j] * l2w[j * OUTF + cc];
    w2l2[k * OUTF + cc] = o;
    if (t < OUTF) {
        float b = l2b[t];
        for (int j = 0; j < F; j++) b += b2[j] * l2w[j * OUTF + t];
        b2l2[t] = b;
    }
    if (t < 33) red[t] = 0.0f;
    if (t == 33) ((unsigned*)red)[33] = 0xFFFFFFFFu;
    if (t == 34) ((unsigned*)red)[34] = 0u;
}

// pass 1: per-block LDS histogram of dst>>8 over this block's private chunk
__global__ __launch_bounds__(256) void k_hist(const int* __restrict__ dst, int* __restrict__ hist,
                                              int E, int NBK) {
    __shared__ int lh[512];
    int t = threadIdx.x, blk = blockIdx.x;
    for (int b = t; b < NBK; b += 256) lh[b] = 0;
    __syncthreads();
    int chunk = (E + PB - 1) / PB;
    int beg = blk * chunk, end = min(beg + chunk, E);
    for (int e = beg + t; e < end; e += 256) atomicAdd(&lh[__builtin_nontemporal_load(dst + e) >> 8], 1);
    __syncthreads();
    for (int b = t; b < NBK; b += 256) hist[blk * NBK + b] = lh[b];  // dense coalesced
}

// per-bucket exclusive scan across the PB blocks (one block per bucket)
__global__ __launch_bounds__(PB) void k_hscan1(int* __restrict__ hist, int* __restrict__ btot, int NBK) {
    __shared__ int s[PB];
    int b = blockIdx.x, t = threadIdx.x;
    int v = hist[t * NBK + b];
    s[t] = v;
    __syncthreads();
    for (int off = 1; off < PB; off <<= 1) {
        int u = (t >= off) ? s[t - off] : 0;
        __syncthreads();
        s[t] += u;
        __syncthreads();
    }
    hist[t * NBK + b] = s[t] - v;  // exclusive within bucket
    if (t == PB - 1) btot[b] = s[t];
}

// scan bucket totals -> bbase (1 block; NBK <= 512)
__global__ void k_hscan2(const int* __restrict__ btot, int* __restrict__ bbase, int NBK) {
    __shared__ int s[512];
    int t = threadIdx.x;
    int v = (t < NBK) ? btot[t] : 0;
    s[t] = v;
    __syncthreads();
    for (int off = 1; off < 512; off <<= 1) {
        int u = (t >= off) ? s[t - off] : 0;
        __syncthreads();
        s[t] += u;
        __syncthreads();
    }
    if (t < NBK) {
        bbase[t] = s[t] - v;
        if (t == NBK - 1) bbase[NBK] = s[t];
    }
}

// pass 2: private cursors in LDS (hist offset + bucket base); single-writer lines
__global__ __launch_bounds__(256) void k_place(const int* __restrict__ src, const int* __restrict__ dst,
                                               const int* __restrict__ hist, const int* __restrict__ bbase,
                                               unsigned* __restrict__ bucketArr, int E, int NBK) {
    __shared__ int cur[512];
    int t = threadIdx.x, blk = blockIdx.x;
    for (int b = t; b < NBK; b += 256) cur[b] = hist[blk * NBK + b] + bbase[b];
    __syncthreads();
    int chunk = (E + PB - 1) / PB;
    int beg = blk * chunk, end = min(beg + chunk, E);
    for (int e = beg + t; e < end; e += 256) {
        int d = __builtin_nontemporal_load(dst + e);
        int sidx = __builtin_nontemporal_load(src + e);
        int p = atomicAdd(&cur[d >> 8], 1);
        bucketArr[p] = ((unsigned)sidx << 8) | (unsigned)(d & 255);
    }
}

// one block per bucket: LDS count -> scan -> place. Emits CSR eidx + meta{beg,deg,dinv}.
__global__ __launch_bounds__(256) void k_binsort(const unsigned* __restrict__ bucketArr,
                                                 const int* __restrict__ bbase,
                                                 int* __restrict__ eidx, int4* __restrict__ meta, int N) {
    __shared__ unsigned ledge[LEDGE];
    __shared__ int lcnt[256], lofs[256], lcur[256], lscan[256];
    int b = blockIdx.x, t = threadIdx.x;
    int gb = bbase[b];
    int count = min(bbase[b + 1] - gb, LEDGE);
    for (int j = t; j < count; j += 256) ledge[j] = __builtin_nontemporal_load(bucketArr + gb + j);
    lcnt[t] = 0;
    __syncthreads();
    for (int j = t; j < count; j += 256) atomicAdd(&lcnt[ledge[j] & 255u], 1);
    __syncthreads();
    int deg = lcnt[t];
    lscan[t] = deg;
    __syncthreads();
    for (int off = 1; off < 256; off <<= 1) {
        int u = (t >= off) ? lscan[t - off] : 0;
        __syncthreads();
        lscan[t] += u;
        __syncthreads();
    }
    lofs[t] = lscan[t] - deg;  // exclusive
    lcur[t] = 0;
    int node = (b << 8) + t;
    if (node < N) meta[node] = make_int4(gb + lofs[t], deg, __float_as_int(rsqrtf((float)deg + 1.0f)), 0);
    __syncthreads();
    for (int j = t; j < count; j += 256) {
        unsigned v = ledge[j];
        int loc = (int)(v & 255u);
        int p = atomicAdd(&lcur[loc], 1);
        eidx[gb + lofs[loc] + p] = (int)(v >> 8);  // single-writer 16KB window
    }
}

// xbf = bf16(x * dinv), 4 channels per thread
__global__ void k_prescale(const float4* __restrict__ x4, const int4* __restrict__ meta,
                           ushort4* __restrict__ xbf4, int total4) {
    int idx = blockIdx.x * blockDim.x + threadIdx.x;
    if (idx < total4) {
        float di = __int_as_float(meta[idx >> 4].z);
        float4 v = x4[idx];
        ushort4 o;
        o.x = f2bf(v.x * di); o.y = f2bf(v.y * di); o.z = f2bf(v.z * di); o.w = f2bf(v.w * di);
        xbf4[idx] = o;
    }
}

// conv1: t1 = bf16( dinv_i * (sum_nbr xbf[s] + xbf[i]) ). wave = 4 nodes x 16 lanes x 4ch.
// 32 slots upfront via 2 nt loads; 4 acc chains; t1 nt-stored (keeps xbf L2-resident).
__global__ __launch_bounds__(256, 4) void k_conv1agg(const unsigned short* __restrict__ xbf,
                                                     const int4* __restrict__ meta,
                                                     const int* __restrict__ eidx,
                                                     unsigned short* __restrict__ t1, int N) {
    int tid = threadIdx.x, wave = tid >> 6, lane = tid & 63;
    int g = lane >> 4, gl = lane & 15, gbase = lane & 48;
    for (int i0 = (blockIdx.x * 4 + wave) * 4; i0 < N; i0 += gridDim.x * 16) {
        int i = i0 + g;
        int beg = 0, dcnt = 0;
        float di = 0.f;
        float4 a0 = make_float4(0.f, 0.f, 0.f, 0.f), a1 = a0, a2 = a0, a3 = a0;
        int ss0 = 0, ss1 = 0;
        if (i < N) {
            int4 m = meta[i];
            beg = m.x; dcnt = m.y; di = __int_as_float(m.z);
            ushort4 v = ((const ushort4*)xbf)[(size_t)i * 16 + gl];  // self
            a0.x = bf2f(v.x); a0.y = bf2f(v.y); a0.z = bf2f(v.z); a0.w = bf2f(v.w);
            ss0 = (gl < dcnt) ? __builtin_nontemporal_load(eidx + beg + gl) : 0;
            ss1 = (16 + gl < dcnt) ? __builtin_nontemporal_load(eidx + beg + 16 + gl) : 0;
        }
#pragma unroll
        for (int k = 0; k < 32; k++) {
            if (k < dcnt) {
                int sv = __shfl((k < 16) ? ss0 : ss1, gbase + (k & 15), 64);
                ushort4 v = ((const ushort4*)xbf)[(size_t)sv * 16 + gl];
                float4* a = (k & 3) == 0 ? &a0 : (k & 3) == 1 ? &a1 : (k & 3) == 2 ? &a2 : &a3;
                a->x += bf2f(v.x); a->y += bf2f(v.y); a->z += bf2f(v.z); a->w += bf2f(v.w);
            }
        }
        for (int base = 32; base < dcnt; base += 16) {  // rare tail
            int j = base + gl;
            int ss = (j < dcnt) ? __builtin_nontemporal_load(eidx + beg + j) : 0;
            int cnt = min(dcnt - base, 16);
#pragma unroll
            for (int k = 0; k < 16; k++) {
                if (k < cnt) {
                    int sv = __shfl(ss, gbase + k, 64);
                    ushort4 v = ((const ushort4*)xbf)[(size_t)sv * 16 + gl];
                    float4* a = (k & 3) == 0 ? &a0 : (k & 3) == 1 ? &a1 : (k & 3) == 2 ? &a2 : &a3;
                    a->x += bf2f(v.x); a->y += bf2f(v.y); a->z += bf2f(v.z); a->w += bf2f(v.w);
                }
            }
        }
        if (i < N) {
            ushort4 o;
            o.x = f2bf((a0.x + a1.x + a2.x + a3.x) * di);
            o.y = f2bf((a0.y + a1.y + a2.y + a3.y) * di);
            o.z = f2bf((a0.z + a1.z + a2.z + a3.z) * di);
            o.w = f2bf((a0.w + a1.w + a2.w + a3.w) * di);
            __builtin_nontemporal_store(us4_u64(o), (unsigned long long*)(t1 + (size_t)i * F + gl * 4));
        }
    }
}

// dense per-node dual GEMM: z2 = bf16( (ReLU(gs*(t1@W1)+bias1)*dinv) @ w2l2 )
// t1 nt-loaded (single-use); z2 stored normally (about to be gathered).
__global__ __launch_bounds__(256, 2) void k_z(const unsigned short* __restrict__ t1,
                                              const int4* __restrict__ meta,
                                              const float* __restrict__ W1, const float* __restrict__ b1,
                                              const float* __restrict__ gamma, const float* __restrict__ beta,
                                              const float* __restrict__ w2l2, unsigned short* __restrict__ z2, int N) {
    __shared__ __align__(16) float tb[4][F];
    __shared__ __align__(16) float hb[4][F];
    int tid = threadIdx.x, wave = tid >> 6, lane = tid & 63, cc = lane & 31;
    float gs = gamma[lane] * BN_INV;
    float bias1 = fmaf(b1[lane], gs, beta[lane]);
    float w1reg[F], w2reg[F];
#pragma unroll
    for (int k = 0; k < F; k++) w1reg[k] = W1[k * F + lane] * gs;
#pragma unroll
    for (int k = 0; k < F; k++) w2reg[k] = w2l2[k * OUTF + cc];

    for (int r = blockIdx.x * 4 + wave; r < N; r += gridDim.x * 4) {
        float di = __int_as_float(meta[r].z);
        tb[wave][lane] = bf2f(__builtin_nontemporal_load(t1 + (size_t)r * F + lane));
        float o = bias1;
        const float4* t4 = (const float4*)tb[wave];
#pragma unroll
        for (int k4 = 0; k4 < 16; k4++) {
            float4 tv = t4[k4];  // broadcast
            o = fmaf(tv.x, w1reg[4 * k4 + 0], o);
            o = fmaf(tv.y, w1reg[4 * k4 + 1], o);
            o = fmaf(tv.z, w1reg[4 * k4 + 2], o);
            o = fmaf(tv.w, w1reg[4 * k4 + 3], o);
        }
        hb[wave][lane] = fmaxf(o, 0.0f) * di;  // h row
        float z = 0.0f;
        const float4* h4 = (const float4*)hb[wave];
#pragma unroll
        for (int k4 = 0; k4 < 16; k4++) {
            float4 hv = h4[k4];
            z = fmaf(hv.x, w2reg[4 * k4 + 0], z);
            z = fmaf(hv.y, w2reg[4 * k4 + 1], z);
            z = fmaf(hv.z, w2reg[4 * k4 + 2], z);
            z = fmaf(hv.w, w2reg[4 * k4 + 3], z);
        }
        if (lane < 32) z2[(size_t)r * OUTF + lane] = f2bf(z);
    }
}

// conv2: slim gather of bf16 z2 (64 B rows). wave = 8 nodes x 8 lanes x 4ch.
// 24 slots upfront via 3 nt loads; logits stored bf16 nt; wraw nt.
__global__ __launch_bounds__(256, 4) void k_conv2agg(const unsigned short* __restrict__ z2,
                                                     const int4* __restrict__ meta,
                                                     const int* __restrict__ eidx, const float* __restrict__ b2l2,
                                                     unsigned short* __restrict__ logits_bf, float* __restrict__ wraw,
                                                     unsigned* __restrict__ redmm, int N) {
    __shared__ float smn[4], smx[4];
    int tid = threadIdx.x, wave = tid >> 6, lane = tid & 63;
    int g = lane >> 3, gl = lane & 7, gbase = lane & 56;
    float4 bvec = ((const float4*)b2l2)[gl];
    float mn = INFINITY, mx = -INFINITY;
    for (int i0 = (blockIdx.x * 4 + wave) * 8; i0 < N; i0 += gridDim.x * 32) {
        int i = i0 + g;
        int beg = 0, dcnt = 0;
        float di = 0.f;
        float4 a0 = make_float4(0.f, 0.f, 0.f, 0.f), a1 = a0, a2 = a0, a3 = a0;
        int ss0 = 0, ss1 = 0, ss2 = 0;
        if (i < N) {
            int4 m = meta[i];
            beg = m.x; dcnt = m.y; di = __int_as_float(m.z);
            ushort4 v = ((const ushort4*)(z2 + (size_t)i * OUTF))[gl];  // self
            a0.x = bf2f(v.x); a0.y = bf2f(v.y); a0.z = bf2f(v.z); a0.w = bf2f(v.w);
            ss0 = (gl < dcnt) ? __builtin_nontemporal_load(eidx + beg + gl) : 0;
            ss1 = (8 + gl < dcnt) ? __builtin_nontemporal_load(eidx + beg + 8 + gl) : 0;
            ss2 = (16 + gl < dcnt) ? __builtin_nontemporal_load(eidx + beg + 16 + gl) : 0;
        }
#pragma unroll
        for (int k = 0; k < 24; k++) {
            if (k < dcnt) {
                int sv = __shfl((k < 8) ? ss0 : (k < 16) ? ss1 : ss2, gbase + (k & 7), 64);
                ushort4 v = ((const ushort4*)(z2 + (size_t)sv * OUTF))[gl];
                float4* a = (k & 3) == 0 ? &a0 : (k & 3) == 1 ? &a1 : (k & 3) == 2 ? &a2 : &a3;
                a->x += bf2f(v.x); a->y += bf2f(v.y); a->z += bf2f(v.z); a->w += bf2f(v.w);
            }
        }
        for (int base = 24; base < dcnt; base += 8) {  // rare tail
            int j = base + gl;
            int ss = (j < dcnt) ? __builtin_nontemporal_load(eidx + beg + j) : 0;
            int cnt = min(dcnt - base, 8);
#pragma unroll
            for (int k = 0; k < 8; k++) {
                if (k < cnt) {
                    int sv = __shfl(ss, gbase + k, 64);
                    ushort4 v = ((const ushort4*)(z2 + (size_t)sv * OUTF))[gl];
                    float4* a = (k & 3) == 0 ? &a0 : (k & 3) == 1 ? &a1 : (k & 3) == 2 ? &a2 : &a3;
                    a->x += bf2f(v.x); a->y += bf2f(v.y); a->z += bf2f(v.z); a->w += bf2f(v.w);
                }
            }
        }
        float4 lg;
        lg.x = fmaf(a0.x + a1.x + a2.x + a3.x, di, bvec.x);
        lg.y = fmaf(a0.y + a1.y + a2.y + a3.y, di, bvec.y);
        lg.z = fmaf(a0.z + a1.z + a2.z + a3.z, di, bvec.z);
        lg.w = fmaf(a0.w + a1.w + a2.w + a3.w, di, bvec.w);
        if (i < N) {
            ushort4 ob;
            ob.x = f2bf(lg.x); ob.y = f2bf(lg.y); ob.z = f2bf(lg.z); ob.w = f2bf(lg.w);
            __builtin_nontemporal_store(us4_u64(ob), (unsigned long long*)(logits_bf + (size_t)i * OUTF + gl * 4));
        }
        // softmax + entropy over 32 logits spread across 8 lanes x 4
        float m4 = fmaxf(fmaxf(lg.x, lg.y), fmaxf(lg.z, lg.w));
        for (int off = 4; off > 0; off >>= 1) m4 = fmaxf(m4, __shfl_xor(m4, off, 8));
        float p0 = expf(lg.x - m4), p1 = expf(lg.y - m4), p2 = expf(lg.z - m4), p3 = expf(lg.w - m4);
        float s4 = p0 + p1 + p2 + p3;
        for (int off = 4; off > 0; off >>= 1) s4 += __shfl_xor(s4, off, 8);
        float inv = 1.0f / s4;
        float t0 = p0 * inv, t1v = p1 * inv, t2v = p2 * inv, t3 = p3 * inv;
        float e4 = t0 * logf(t0 + 1e-9f) + t1v * logf(t1v + 1e-9f) + t2v * logf(t2v + 1e-9f) + t3 * logf(t3 + 1e-9f);
        for (int off = 4; off > 0; off >>= 1) e4 += __shfl_xor(e4, off, 8);
        float w = 1.0f / (-e4 + 1e-10f);
        if (i < N) {
            if (gl == 0) __builtin_nontemporal_store(w, wraw + i);
            mn = fminf(mn, w);
            mx = fmaxf(mx, w);
        }
    }
    for (int off = 32; off > 0; off >>= 1) {
        mn = fminf(mn, __shfl_xor(mn, off, 64));
        mx = fmaxf(mx, __shfl_xor(mx, off, 64));
    }
    if (lane == 0) { smn[wave] = mn; smx[wave] = mx; }
    __syncthreads();
    if (tid == 0) {
        float a = fminf(fminf(smn[0], smn[1]), fminf(smn[2], smn[3]));
        float b = fmaxf(fmaxf(smx[0], smx[1]), fmaxf(smx[2], smx[3]));
        atomicMin(&redmm[33], fenc(a));
        atomicMax(&redmm[34], fenc(b));
    }
}

__global__ __launch_bounds__(256) void k_weight(const unsigned short* __restrict__ logits_bf,
                                                const float* __restrict__ wraw,
                                                float* __restrict__ red, int N) {
    const unsigned* mm = (const unsigned*)red;
    float mn = fdec(mm[33]), mx = fdec(mm[34]);
    float inv = 1.0f / (mx - mn);
    int c = threadIdx.x & 31;
    int g = threadIdx.x >> 5;  // 8 row-groups
    float acc = 0.0f, es = 0.0f;
    for (int r = blockIdx.x * 8 + g; r < N; r += gridDim.x * 8) {
        float e = expf((__builtin_nontemporal_load(wraw + r) - mn) * inv);
        acc += e * bf2f(__builtin_nontemporal_load(logits_bf + (size_t)r * OUTF + c));
        if (c == 0) es += e;
    }
    __shared__ float sa[8][OUTF];
    __shared__ float se[8];
    sa[g][c] = acc;
    if (c == 0) se[g] = es;
    __syncthreads();
    if (g == 0) {
        float t = sa[0][c];
#pragma unroll
        for (int i = 1; i < 8; i++) t += sa[i][c];
        unsafeAtomicAdd(&red[c], t);
        if (c == 0) {
            float u = 0.0f;
#pragma unroll
            for (int i = 0; i < 8; i++) u += se[i];
            unsafeAtomicAdd(&red[32], u);
        }
    }
}

__global__ void k_final(const float* __restrict__ red, const float* __restrict__ w3,
                        const float* __restrict__ b3, float* __restrict__ out) {
    int j = threadIdx.x;  // 64 threads
    float s = red[32];
    float o = b3[j];
#pragma unroll
    for (int cc = 0; cc < OUTF; cc++) o += (red[cc] / s) * w3[cc * F + j];
    out[j] = o;
}

extern "C" void kernel_launch(void* const* d_in, const int* in_sizes, int n_in,
                              void* d_out, int out_size, void* d_ws, size_t ws_size,
                              hipStream_t stream) {
    const float* x     = (const float*)d_in[0];
    const int*   ei    = (const int*)d_in[1];
    const float* W1    = (const float*)d_in[2];
    const float* b1    = (const float*)d_in[3];
    const float* gamma = (const float*)d_in[4];
    const float* beta  = (const float*)d_in[5];
    const float* W2    = (const float*)d_in[6];
    const float* b2    = (const float*)d_in[7];
    const float* l2w   = (const float*)d_in[8];
    const float* l2b   = (const float*)d_in[9];
    const float* l3w   = (const float*)d_in[10];
    const float* l3b   = (const float*)d_in[11];

    int N = in_sizes[0] / F;
    int E = in_sizes[1] / 2;
    const int* src = ei;
    const int* dst = ei + E;
    int NBK = (N + 255) >> 8;  // 391 buckets of 256 nodes (<=512 assumed)

    // workspace layout (16B-aligned chunks)
    char* p = (char*)d_ws;
    int* hist = (int*)p;                p += (size_t)PB * NBK * 4;
    int* btot = (int*)p;                p += 512 * 4;
    int* bbase = (int*)p;               p += 516 * 4;
    unsigned* bucketArr = (unsigned*)p; p += (size_t)E * 4;
    int4* meta = (int4*)p;              p += (size_t)N * 16;
    int* eidx = (int*)p;                p += (size_t)E * 4;
    float* red = (float*)p;             p += 64 * 4;
    float* w2l2 = (float*)p;            p += F * OUTF * 4;
    float* b2l2 = (float*)p;            p += OUTF * 4 + 32;
    unsigned short* xbf = (unsigned short*)p;  p += (size_t)N * F * 2;  // aliased by z2
    unsigned short* t1 = (unsigned short*)p;   p += (size_t)N * F * 2;  // aliased by logits
    float* wraw = (float*)p;            p += (size_t)N * 4;
    unsigned short* z2 = xbf;                  // xbf dead after conv1agg
    unsigned short* logits_bf = t1;            // t1 dead after k_z

    // setup + privatized counting-sort CSR build
    k_fuse<<<8, 256, 0, stream>>>(W2, b2, l2w, l2b, w2l2, b2l2, red);
    k_hist<<<PB, 256, 0, stream>>>(dst, hist, E, NBK);
    k_hscan1<<<NBK, PB, 0, stream>>>(hist, btot, NBK);
    k_hscan2<<<1, 512, 0, stream>>>(btot, bbase, NBK);
    k_place<<<PB, 256, 0, stream>>>(src, dst, hist, bbase, bucketArr, E, NBK);
    k_binsort<<<NBK, 256, 0, stream>>>(bucketArr, bbase, eidx, meta, N);
    k_prescale<<<(N * 16 + 255) / 256, 256, 0, stream>>>((const float4*)x, meta, (ushort4*)xbf, N * 16);

    // convs
    k_conv1agg<<<2048, 256, 0, stream>>>(xbf, meta, eidx, t1, N);
    k_z<<<1024, 256, 0, stream>>>(t1, meta, W1, b1, gamma, beta, w2l2, z2, N);
    k_conv2agg<<<2048, 256, 0, stream>>>(z2, meta, eidx, b2l2, logits_bf, wraw, (unsigned*)red, N);

    // pooling head
    k_weight<<<1024, 256, 0, stream>>>(logits_bf, wraw, red, N);
    k_final<<<1, 64, 0, stream>>>(red, l3w, l3b, (float*)d_out);
}

// Round 11
// 371.609 us; speedup vs baseline: 1.0741x; 1.0741x over previous
//
#include <hip/hip_runtime.h>
#include <hip/hip_bf16.h>
#include <math.h>

// GCN. CSR via block-privatized 2-pass counting sort (single-writer lines).
// r11: r9 structure (all r10 nt-hints reverted — nt loads on the eidx critical
// chain added HBM latency, 370->399). New: branchless gather bursts (loads
// unconditional w/ clamped addresses, only the accumulate predicated) so the
// compiler can hoist the full 24/32-load burst (r9 VGPR=36 showed it issued in
// shallow batches behind `if(k<dcnt)` guards). logits stored bf16 (normal).

#define F 64
#define OUTF 32
#define PB 128            // edge-partition blocks (privatized sort)
#define LEDGE 5632        // per-bucket LDS capacity (mean 4096)
#define BN_INV 0.9999950000374997f  // rsqrt(1 + 1e-5)

__device__ __forceinline__ unsigned fenc(float f) {
    unsigned u = __float_as_uint(f);
    return (u & 0x80000000u) ? ~u : (u | 0x80000000u);
}
__device__ __forceinline__ float fdec(unsigned e) {
    return (e & 0x80000000u) ? __uint_as_float(e & 0x7fffffffu) : __uint_as_float(~e);
}
__device__ __forceinline__ unsigned short f2bf(float f) {  // RNE
    unsigned u = __float_as_uint(f);
    return (unsigned short)((u + 0x7fffu + ((u >> 16) & 1u)) >> 16);
}
__device__ __forceinline__ float bf2f(unsigned short h) {
    return __uint_as_float((unsigned)h << 16);
}

// red layout: [0..31] acc_c, [32] esum, [33] min-enc(uint), [34] max-enc(uint)

__global__ void k_fuse(const float* __restrict__ W2, const float* __restrict__ b2,
                       const float* __restrict__ l2w, const float* __restrict__ l2b,
                       float* __restrict__ w2l2, float* __restrict__ b2l2, float* __restrict__ red) {
    int t = blockIdx.x * blockDim.x + threadIdx.x;  // 2048 threads
    int k = t >> 5, cc = t & 31;
    float o = 0.0f;
    for (int j = 0; j < F; j++) o += W2[k * F + j] * l2w[j * OUTF + cc];
    w2l2[k * OUTF + cc] = o;
    if (t < OUTF) {
        float b = l2b[t];
        for (int j = 0; j < F; j++) b += b2[j] * l2w[j * OUTF + t];
        b2l2[t] = b;
    }
    if (t < 33) red[t] = 0.0f;
    if (t == 33) ((unsigned*)red)[33] = 0xFFFFFFFFu;
    if (t == 34) ((unsigned*)red)[34] = 0u;
}

// pass 1: per-block LDS histogram of dst>>8 over this block's private chunk
__global__ __launch_bounds__(256) void k_hist(const int* __restrict__ dst, int* __restrict__ hist,
                                              int E, int NBK) {
    __shared__ int lh[512];
    int t = threadIdx.x, blk = blockIdx.x;
    for (int b = t; b < NBK; b += 256) lh[b] = 0;
    __syncthreads();
    int chunk = (E + PB - 1) / PB;
    int beg = blk * chunk, end = min(beg + chunk, E);
    for (int e = beg + t; e < end; e += 256) atomicAdd(&lh[dst[e] >> 8], 1);
    __syncthreads();
    for (int b = t; b < NBK; b += 256) hist[blk * NBK + b] = lh[b];  // dense coalesced
}

// per-bucket exclusive scan across the PB blocks (one block per bucket)
__global__ __launch_bounds__(PB) void k_hscan1(int* __restrict__ hist, int* __restrict__ btot, int NBK) {
    __shared__ int s[PB];
    int b = blockIdx.x, t = threadIdx.x;
    int v = hist[t * NBK + b];
    s[t] = v;
    __syncthreads();
    for (int off = 1; off < PB; off <<= 1) {
        int u = (t >= off) ? s[t - off] : 0;
        __syncthreads();
        s[t] += u;
        __syncthreads();
    }
    hist[t * NBK + b] = s[t] - v;  // exclusive within bucket
    if (t == PB - 1) btot[b] = s[t];
}

// scan bucket totals -> bbase (1 block; NBK <= 512)
__global__ void k_hscan2(const int* __restrict__ btot, int* __restrict__ bbase, int NBK) {
    __shared__ int s[512];
    int t = threadIdx.x;
    int v = (t < NBK) ? btot[t] : 0;
    s[t] = v;
    __syncthreads();
    for (int off = 1; off < 512; off <<= 1) {
        int u = (t >= off) ? s[t - off] : 0;
        __syncthreads();
        s[t] += u;
        __syncthreads();
    }
    if (t < NBK) {
        bbase[t] = s[t] - v;
        if (t == NBK - 1) bbase[NBK] = s[t];
    }
}

// pass 2: private cursors in LDS (hist offset + bucket base); single-writer lines
__global__ __launch_bounds__(256) void k_place(const int* __restrict__ src, const int* __restrict__ dst,
                                               const int* __restrict__ hist, const int* __restrict__ bbase,
                                               unsigned* __restrict__ bucketArr, int E, int NBK) {
    __shared__ int cur[512];
    int t = threadIdx.x, blk = blockIdx.x;
    for (int b = t; b < NBK; b += 256) cur[b] = hist[blk * NBK + b] + bbase[b];
    __syncthreads();
    int chunk = (E + PB - 1) / PB;
    int beg = blk * chunk, end = min(beg + chunk, E);
    for (int e = beg + t; e < end; e += 256) {
        int d = dst[e], sidx = src[e];
        int p = atomicAdd(&cur[d >> 8], 1);
        bucketArr[p] = ((unsigned)sidx << 8) | (unsigned)(d & 255);
    }
}

// one block per bucket: LDS count -> scan -> place. Emits CSR eidx + meta{beg,deg,dinv}.
__global__ __launch_bounds__(256) void k_binsort(const unsigned* __restrict__ bucketArr,
                                                 const int* __restrict__ bbase,
                                                 int* __restrict__ eidx, int4* __restrict__ meta, int N) {
    __shared__ unsigned ledge[LEDGE];
    __shared__ int lcnt[256], lofs[256], lcur[256], lscan[256];
    int b = blockIdx.x, t = threadIdx.x;
    int gb = bbase[b];
    int count = min(bbase[b + 1] - gb, LEDGE);
    for (int j = t; j < count; j += 256) ledge[j] = bucketArr[gb + j];
    lcnt[t] = 0;
    __syncthreads();
    for (int j = t; j < count; j += 256) atomicAdd(&lcnt[ledge[j] & 255u], 1);
    __syncthreads();
    int deg = lcnt[t];
    lscan[t] = deg;
    __syncthreads();
    for (int off = 1; off < 256; off <<= 1) {
        int u = (t >= off) ? lscan[t - off] : 0;
        __syncthreads();
        lscan[t] += u;
        __syncthreads();
    }
    lofs[t] = lscan[t] - deg;  // exclusive
    lcur[t] = 0;
    int node = (b << 8) + t;
    if (node < N) meta[node] = make_int4(gb + lofs[t], deg, __float_as_int(rsqrtf((float)deg + 1.0f)), 0);
    __syncthreads();
    for (int j = t; j < count; j += 256) {
        unsigned v = ledge[j];
        int loc = (int)(v & 255u);
        int p = atomicAdd(&lcur[loc], 1);
        eidx[gb + lofs[loc] + p] = (int)(v >> 8);  // single-writer 16KB window
    }
}

// xbf = bf16(x * dinv), 4 channels per thread
__global__ void k_prescale(const float4* __restrict__ x4, const int4* __restrict__ meta,
                           ushort4* __restrict__ xbf4, int total4) {
    int idx = blockIdx.x * blockDim.x + threadIdx.x;
    if (idx < total4) {
        float di = __int_as_float(meta[idx >> 4].z);
        float4 v = x4[idx];
        ushort4 o;
        o.x = f2bf(v.x * di); o.y = f2bf(v.y * di); o.z = f2bf(v.z * di); o.w = f2bf(v.w * di);
        xbf4[idx] = o;
    }
}

// conv1: t1 = bf16( dinv_i * (sum_nbr xbf[s] + xbf[i]) ). wave = 4 nodes x 16 lanes x 4ch.
// Branchless burst: 32 unconditional row loads (invalid slots -> own row, L2-hot).
__global__ __launch_bounds__(256) void k_conv1agg(const unsigned short* __restrict__ xbf,
                                                  const int4* __restrict__ meta,
                                                  const int* __restrict__ eidx,
                                                  unsigned short* __restrict__ t1, int N, int Em1) {
    int tid = threadIdx.x, wave = tid >> 6, lane = tid & 63;
    int g = lane >> 4, gl = lane & 15, gbase = lane & 48;
    for (int i0 = (blockIdx.x * 4 + wave) * 4; i0 < N; i0 += gridDim.x * 16) {
        int i = i0 + g;
        int iclamp = min(i, N - 1);
        int beg = 0, dcnt = 0;
        float di = 0.f;
        float4 a0 = make_float4(0.f, 0.f, 0.f, 0.f), a1 = a0, a2 = a0, a3 = a0;
        if (i < N) {
            int4 m = meta[i];
            beg = m.x; dcnt = m.y; di = __int_as_float(m.z);
        }
        {
            ushort4 v = ((const ushort4*)xbf)[(size_t)iclamp * 16 + gl];  // self
            if (i < N) { a0.x = bf2f(v.x); a0.y = bf2f(v.y); a0.z = bf2f(v.z); a0.w = bf2f(v.w); }
        }
        int ss0 = eidx[min(beg + gl, Em1)];
        int ss1 = eidx[min(beg + 16 + gl, Em1)];
#pragma unroll
        for (int k = 0; k < 32; k++) {
            int sv = __shfl((k < 16) ? ss0 : ss1, gbase + (k & 15), 64);
            sv = (k < dcnt) ? sv : iclamp;  // invalid slot -> own row (hot line)
            ushort4 v = ((const ushort4*)xbf)[(size_t)sv * 16 + gl];
            if (k < dcnt) {
                float4* a = (k & 3) == 0 ? &a0 : (k & 3) == 1 ? &a1 : (k & 3) == 2 ? &a2 : &a3;
                a->x += bf2f(v.x); a->y += bf2f(v.y); a->z += bf2f(v.z); a->w += bf2f(v.w);
            }
        }
        for (int base = 32; base < dcnt; base += 16) {  // rare tail
            int j = base + gl;
            int ss = eidx[min(beg + j, Em1)];
            int cnt = min(dcnt - base, 16);
#pragma unroll
            for (int k = 0; k < 16; k++) {
                if (k < cnt) {
                    int sv = __shfl(ss, gbase + k, 64);
                    ushort4 v = ((const ushort4*)xbf)[(size_t)sv * 16 + gl];
                    float4* a = (k & 3) == 0 ? &a0 : (k & 3) == 1 ? &a1 : (k & 3) == 2 ? &a2 : &a3;
                    a->x += bf2f(v.x); a->y += bf2f(v.y); a->z += bf2f(v.z); a->w += bf2f(v.w);
                }
            }
        }
        if (i < N) {
            ushort4 o;
            o.x = f2bf((a0.x + a1.x + a2.x + a3.x) * di);
            o.y = f2bf((a0.y + a1.y + a2.y + a3.y) * di);
            o.z = f2bf((a0.z + a1.z + a2.z + a3.z) * di);
            o.w = f2bf((a0.w + a1.w + a2.w + a3.w) * di);
            ((ushort4*)t1)[(size_t)i * 16 + gl] = o;
        }
    }
}

// dense per-node dual GEMM: z2 = bf16( (ReLU(gs*(t1@W1)+bias1)*dinv) @ w2l2 )
__global__ __launch_bounds__(256, 2) void k_z(const unsigned short* __restrict__ t1,
                                              const int4* __restrict__ meta,
                                              const float* __restrict__ W1, const float* __restrict__ b1,
                                              const float* __restrict__ gamma, const float* __restrict__ beta,
                                              const float* __restrict__ w2l2, unsigned short* __restrict__ z2, int N) {
    __shared__ __align__(16) float tb[4][F];
    __shared__ __align__(16) float hb[4][F];
    int tid = threadIdx.x, wave = tid >> 6, lane = tid & 63, cc = lane & 31;
    float gs = gamma[lane] * BN_INV;
    float bias1 = fmaf(b1[lane], gs, beta[lane]);
    float w1reg[F], w2reg[F];
#pragma unroll
    for (int k = 0; k < F; k++) w1reg[k] = W1[k * F + lane] * gs;
#pragma unroll
    for (int k = 0; k < F; k++) w2reg[k] = w2l2[k * OUTF + cc];

    for (int r = blockIdx.x * 4 + wave; r < N; r += gridDim.x * 4) {
        float di = __int_as_float(meta[r].z);
        tb[wave][lane] = bf2f(t1[(size_t)r * F + lane]);
        float o = bias1;
        const float4* t4 = (const float4*)tb[wave];
#pragma unroll
        for (int k4 = 0; k4 < 16; k4++) {
            float4 tv = t4[k4];  // broadcast
            o = fmaf(tv.x, w1reg[4 * k4 + 0], o);
            o = fmaf(tv.y, w1reg[4 * k4 + 1], o);
            o = fmaf(tv.z, w1reg[4 * k4 + 2], o);
            o = fmaf(tv.w, w1reg[4 * k4 + 3], o);
        }
        hb[wave][lane] = fmaxf(o, 0.0f) * di;  // h row
        float z = 0.0f;
        const float4* h4 = (const float4*)hb[wave];
#pragma unroll
        for (int k4 = 0; k4 < 16; k4++) {
            float4 hv = h4[k4];
            z = fmaf(hv.x, w2reg[4 * k4 + 0], z);
            z = fmaf(hv.y, w2reg[4 * k4 + 1], z);
            z = fmaf(hv.z, w2reg[4 * k4 + 2], z);
            z = fmaf(hv.w, w2reg[4 * k4 + 3], z);
        }
        if (lane < 32) z2[(size_t)r * OUTF + lane] = f2bf(z);
    }
}

// conv2: slim gather of bf16 z2 (64 B rows). wave = 8 nodes x 8 lanes x 4ch.
// Branchless burst of 24 unconditional loads; logits stored bf16; fused head.
__global__ __launch_bounds__(256) void k_conv2agg(const unsigned short* __restrict__ z2,
                                                  const int4* __restrict__ meta,
                                                  const int* __restrict__ eidx, const float* __restrict__ b2l2,
                                                  unsigned short* __restrict__ logits_bf, float* __restrict__ wraw,
                                                  unsigned* __restrict__ redmm, int N, int Em1) {
    __shared__ float smn[4], smx[4];
    int tid = threadIdx.x, wave = tid >> 6, lane = tid & 63;
    int g = lane >> 3, gl = lane & 7, gbase = lane & 56;
    float4 bvec = ((const float4*)b2l2)[gl];
    float mn = INFINITY, mx = -INFINITY;
    for (int i0 = (blockIdx.x * 4 + wave) * 8; i0 < N; i0 += gridDim.x * 32) {
        int i = i0 + g;
        int iclamp = min(i, N - 1);
        int beg = 0, dcnt = 0;
        float di = 0.f;
        float4 a0 = make_float4(0.f, 0.f, 0.f, 0.f), a1 = a0, a2 = a0, a3 = a0;
        if (i < N) {
            int4 m = meta[i];
            beg = m.x; dcnt = m.y; di = __int_as_float(m.z);
        }
        {
            ushort4 v = ((const ushort4*)(z2 + (size_t)iclamp * OUTF))[gl];  // self
            if (i < N) { a0.x = bf2f(v.x); a0.y = bf2f(v.y); a0.z = bf2f(v.z); a0.w = bf2f(v.w); }
        }
        int ss0 = eidx[min(beg + gl, Em1)];
        int ss1 = eidx[min(beg + 8 + gl, Em1)];
        int ss2 = eidx[min(beg + 16 + gl, Em1)];
#pragma unroll
        for (int k = 0; k < 24; k++) {
            int sv = __shfl((k < 8) ? ss0 : (k < 16) ? ss1 : ss2, gbase + (k & 7), 64);
            sv = (k < dcnt) ? sv : iclamp;  // invalid slot -> own row (hot line)
            ushort4 v = ((const ushort4*)(z2 + (size_t)sv * OUTF))[gl];
            if (k < dcnt) {
                float4* a = (k & 3) == 0 ? &a0 : (k & 3) == 1 ? &a1 : (k & 3) == 2 ? &a2 : &a3;
                a->x += bf2f(v.x); a->y += bf2f(v.y); a->z += bf2f(v.z); a->w += bf2f(v.w);
            }
        }
        for (int base = 24; base < dcnt; base += 8) {  // rare tail
            int j = base + gl;
            int ss = eidx[min(beg + j, Em1)];
            int cnt = min(dcnt - base, 8);
#pragma unroll
            for (int k = 0; k < 8; k++) {
                if (k < cnt) {
                    int sv = __shfl(ss, gbase + k, 64);
                    ushort4 v = ((const ushort4*)(z2 + (size_t)sv * OUTF))[gl];
                    float4* a = (k & 3) == 0 ? &a0 : (k & 3) == 1 ? &a1 : (k & 3) == 2 ? &a2 : &a3;
                    a->x += bf2f(v.x); a->y += bf2f(v.y); a->z += bf2f(v.z); a->w += bf2f(v.w);
                }
            }
        }
        float4 lg;
        lg.x = fmaf(a0.x + a1.x + a2.x + a3.x, di, bvec.x);
        lg.y = fmaf(a0.y + a1.y + a2.y + a3.y, di, bvec.y);
        lg.z = fmaf(a0.z + a1.z + a2.z + a3.z, di, bvec.z);
        lg.w = fmaf(a0.w + a1.w + a2.w + a3.w, di, bvec.w);
        if (i < N) {
            ushort4 ob;
            ob.x = f2bf(lg.x); ob.y = f2bf(lg.y); ob.z = f2bf(lg.z); ob.w = f2bf(lg.w);
            ((ushort4*)(logits_bf + (size_t)i * OUTF))[gl] = ob;
        }
        // softmax + entropy over 32 logits spread across 8 lanes x 4
        float m4 = fmaxf(fmaxf(lg.x, lg.y), fmaxf(lg.z, lg.w));
        for (int off = 4; off > 0; off >>= 1) m4 = fmaxf(m4, __shfl_xor(m4, off, 8));
        float p0 = expf(lg.x - m4), p1 = expf(lg.y - m4), p2 = expf(lg.z - m4), p3 = expf(lg.w - m4);
        float s4 = p0 + p1 + p2 + p3;
        for (int off = 4; off > 0; off >>= 1) s4 += __shfl_xor(s4, off, 8);
        float inv = 1.0f / s4;
        float t0 = p0 * inv, t1v = p1 * inv, t2v = p2 * inv, t3 = p3 * inv;
        float e4 = t0 * logf(t0 + 1e-9f) + t1v * logf(t1v + 1e-9f) + t2v * logf(t2v + 1e-9f) + t3 * logf(t3 + 1e-9f);
        for (int off = 4; off > 0; off >>= 1) e4 += __shfl_xor(e4, off, 8);
        float w = 1.0f / (-e4 + 1e-10f);
        if (i < N) {
            if (gl == 0) wraw[i] = w;
            mn = fminf(mn, w);
            mx = fmaxf(mx, w);
        }
    }
    for (int off = 32; off > 0; off >>= 1) {
        mn = fminf(mn, __shfl_xor(mn, off, 64));
        mx = fmaxf(mx, __shfl_xor(mx, off, 64));
    }
    if (lane == 0) { smn[wave] = mn; smx[wave] = mx; }
    __syncthreads();
    if (tid == 0) {
        float a = fminf(fminf(smn[0], smn[1]), fminf(smn[2], smn[3]));
        float b = fmaxf(fmaxf(smx[0], smx[1]), fmaxf(smx[2], smx[3]));
        atomicMin(&redmm[33], fenc(a));
        atomicMax(&redmm[34], fenc(b));
    }
}

__global__ __launch_bounds__(256) void k_weight(const unsigned short* __restrict__ logits_bf,
                                                const float* __restrict__ wraw,
                                                float* __restrict__ red, int N) {
    const unsigned* mm = (const unsigned*)red;
    float mn = fdec(mm[33]), mx = fdec(mm[34]);
    float inv = 1.0f / (mx - mn);
    int c = threadIdx.x & 31;
    int g = threadIdx.x >> 5;  // 8 row-groups
    float acc = 0.0f, es = 0.0f;
    for (int r = blockIdx.x * 8 + g; r < N; r += gridDim.x * 8) {
        float e = expf((wraw[r] - mn) * inv);
        acc += e * bf2f(logits_bf[(size_t)r * OUTF + c]);
        if (c == 0) es += e;
    }
    __shared__ float sa[8][OUTF];
    __shared__ float se[8];
    sa[g][c] = acc;
    if (c == 0) se[g] = es;
    __syncthreads();
    if (g == 0) {
        float t = sa[0][c];
#pragma unroll
        for (int i = 1; i < 8; i++) t += sa[i][c];
        unsafeAtomicAdd(&red[c], t);
        if (c == 0) {
            float u = 0.0f;
#pragma unroll
            for (int i = 0; i < 8; i++) u += se[i];
            unsafeAtomicAdd(&red[32], u);
        }
    }
}

__global__ void k_final(const float* __restrict__ red, const float* __restrict__ w3,
                        const float* __restrict__ b3, float* __restrict__ out) {
    int j = threadIdx.x;  // 64 threads
    float s = red[32];
    float o = b3[j];
#pragma unroll
    for (int cc = 0; cc < OUTF; cc++) o += (red[cc] / s) * w3[cc * F + j];
    out[j] = o;
}

extern "C" void kernel_launch(void* const* d_in, const int* in_sizes, int n_in,
                              void* d_out, int out_size, void* d_ws, size_t ws_size,
                              hipStream_t stream) {
    const float* x     = (const float*)d_in[0];
    const int*   ei    = (const int*)d_in[1];
    const float* W1    = (const float*)d_in[2];
    const float* b1    = (const float*)d_in[3];
    const float* gamma = (const float*)d_in[4];
    const float* beta  = (const float*)d_in[5];
    const float* W2    = (const float*)d_in[6];
    const float* b2    = (const float*)d_in[7];
    const float* l2w   = (const float*)d_in[8];
    const float* l2b   = (const float*)d_in[9];
    const float* l3w   = (const float*)d_in[10];
    const float* l3b   = (const float*)d_in[11];

    int N = in_sizes[0] / F;
    int E = in_sizes[1] / 2;
    const int* src = ei;
    const int* dst = ei + E;
    int NBK = (N + 255) >> 8;  // 391 buckets of 256 nodes (<=512 assumed)

    // workspace layout (16B-aligned chunks)
    char* p = (char*)d_ws;
    int* hist = (int*)p;                p += (size_t)PB * NBK * 4;
    int* btot = (int*)p;                p += 512 * 4;
    int* bbase = (int*)p;               p += 516 * 4;
    unsigned* bucketArr = (unsigned*)p; p += (size_t)E * 4;
    int4* meta = (int4*)p;              p += (size_t)N * 16;
    int* eidx = (int*)p;                p += (size_t)E * 4;
    float* red = (float*)p;             p += 64 * 4;
    float* w2l2 = (float*)p;            p += F * OUTF * 4;
    float* b2l2 = (float*)p;            p += OUTF * 4 + 32;
    unsigned short* xbf = (unsigned short*)p;  p += (size_t)N * F * 2;  // aliased by z2
    unsigned short* t1 = (unsigned short*)p;   p += (size_t)N * F * 2;  // aliased by logits
    float* wraw = (float*)p;            p += (size_t)N * 4;
    unsigned short* z2 = xbf;                  // xbf dead after conv1agg
    unsigned short* logits_bf = t1;            // t1 dead after k_z

    // setup + privatized counting-sort CSR build
    k_fuse<<<8, 256, 0, stream>>>(W2, b2, l2w, l2b, w2l2, b2l2, red);
    k_hist<<<PB, 256, 0, stream>>>(dst, hist, E, NBK);
    k_hscan1<<<NBK, PB, 0, stream>>>(hist, btot, NBK);
    k_hscan2<<<1, 512, 0, stream>>>(btot, bbase, NBK);
    k_place<<<PB, 256, 0, stream>>>(src, dst, hist, bbase, bucketArr, E, NBK);
    k_binsort<<<NBK, 256, 0, stream>>>(bucketArr, bbase, eidx, meta, N);
    k_prescale<<<(N * 16 + 255) / 256, 256, 0, stream>>>((const float4*)x, meta, (ushort4*)xbf, N * 16);

    // convs
    k_conv1agg<<<2048, 256, 0, stream>>>(xbf, meta, eidx, t1, N, E - 1);
    k_z<<<1024, 256, 0, stream>>>(t1, meta, W1, b1, gamma, beta, w2l2, z2, N);
    k_conv2agg<<<2048, 256, 0, stream>>>(z2, meta, eidx, b2l2, logits_bf, wraw, (unsigned*)red, N, E - 1);

    // pooling head
    k_weight<<<1024, 256, 0, stream>>>(logits_bf, wraw, red, N);
    k_final<<<1, 64, 0, stream>>>(red, l3w, l3b, (float*)d_out);
}

// Round 12
// 358.794 us; speedup vs baseline: 1.1125x; 1.0357x over previous
//
#include <hip/hip_runtime.h>
#include <hip/hip_bf16.h>
#include <math.h>

// GCN. CSR via block-privatized 2-pass counting sort (single-writer lines).
// r12: force deep gather MLP — explicit ushort4 vbuf[24/32] load burst +
// __builtin_amdgcn_sched_barrier(0) between burst and accumulate, so all row
// loads issue before any use (r9/r11: compiler re-serialized load->add and
// kept VGPR=36 -> ~6 loads in flight -> miss-latency bound at 16G miss/s).
// __launch_bounds__(256,4) gives the 128-VGPR budget the buffer needs.

#define F 64
#define OUTF 32
#define PB 128            // edge-partition blocks (privatized sort)
#define LEDGE 5632        // per-bucket LDS capacity (mean 4096)
#define BN_INV 0.9999950000374997f  // rsqrt(1 + 1e-5)

__device__ __forceinline__ unsigned fenc(float f) {
    unsigned u = __float_as_uint(f);
    return (u & 0x80000000u) ? ~u : (u | 0x80000000u);
}
__device__ __forceinline__ float fdec(unsigned e) {
    return (e & 0x80000000u) ? __uint_as_float(e & 0x7fffffffu) : __uint_as_float(~e);
}
__device__ __forceinline__ unsigned short f2bf(float f) {  // RNE
    unsigned u = __float_as_uint(f);
    return (unsigned short)((u + 0x7fffu + ((u >> 16) & 1u)) >> 16);
}
__device__ __forceinline__ float bf2f(unsigned short h) {
    return __uint_as_float((unsigned)h << 16);
}

// red layout: [0..31] acc_c, [32] esum, [33] min-enc(uint), [34] max-enc(uint)

__global__ void k_fuse(const float* __restrict__ W2, const float* __restrict__ b2,
                       const float* __restrict__ l2w, const float* __restrict__ l2b,
                       float* __restrict__ w2l2, float* __restrict__ b2l2, float* __restrict__ red) {
    int t = blockIdx.x * blockDim.x + threadIdx.x;  // 2048 threads
    int k = t >> 5, cc = t & 31;
    float o = 0.0f;
    for (int j = 0; j < F; j++) o += W2[k * F + j] * l2w[j * OUTF + cc];
    w2l2[k * OUTF + cc] = o;
    if (t < OUTF) {
        float b = l2b[t];
        for (int j = 0; j < F; j++) b += b2[j] * l2w[j * OUTF + t];
        b2l2[t] = b;
    }
    if (t < 33) red[t] = 0.0f;
    if (t == 33) ((unsigned*)red)[33] = 0xFFFFFFFFu;
    if (t == 34) ((unsigned*)red)[34] = 0u;
}

// pass 1: per-block LDS histogram of dst>>8 over this block's private chunk
__global__ __launch_bounds__(256) void k_hist(const int* __restrict__ dst, int* __restrict__ hist,
                                              int E, int NBK) {
    __shared__ int lh[512];
    int t = threadIdx.x, blk = blockIdx.x;
    for (int b = t; b < NBK; b += 256) lh[b] = 0;
    __syncthreads();
    int chunk = (E + PB - 1) / PB;
    int beg = blk * chunk, end = min(beg + chunk, E);
    for (int e = beg + t; e < end; e += 256) atomicAdd(&lh[dst[e] >> 8], 1);
    __syncthreads();
    for (int b = t; b < NBK; b += 256) hist[blk * NBK + b] = lh[b];  // dense coalesced
}

// per-bucket exclusive scan across the PB blocks (one block per bucket)
__global__ __launch_bounds__(PB) void k_hscan1(int* __restrict__ hist, int* __restrict__ btot, int NBK) {
    __shared__ int s[PB];
    int b = blockIdx.x, t = threadIdx.x;
    int v = hist[t * NBK + b];
    s[t] = v;
    __syncthreads();
    for (int off = 1; off < PB; off <<= 1) {
        int u = (t >= off) ? s[t - off] : 0;
        __syncthreads();
        s[t] += u;
        __syncthreads();
    }
    hist[t * NBK + b] = s[t] - v;  // exclusive within bucket
    if (t == PB - 1) btot[b] = s[t];
}

// scan bucket totals -> bbase (1 block; NBK <= 512)
__global__ void k_hscan2(const int* __restrict__ btot, int* __restrict__ bbase, int NBK) {
    __shared__ int s[512];
    int t = threadIdx.x;
    int v = (t < NBK) ? btot[t] : 0;
    s[t] = v;
    __syncthreads();
    for (int off = 1; off < 512; off <<= 1) {
        int u = (t >= off) ? s[t - off] : 0;
        __syncthreads();
        s[t] += u;
        __syncthreads();
    }
    if (t < NBK) {
        bbase[t] = s[t] - v;
        if (t == NBK - 1) bbase[NBK] = s[t];
    }
}

// pass 2: private cursors in LDS (hist offset + bucket base); single-writer lines
__global__ __launch_bounds__(256) void k_place(const int* __restrict__ src, const int* __restrict__ dst,
                                               const int* __restrict__ hist, const int* __restrict__ bbase,
                                               unsigned* __restrict__ bucketArr, int E, int NBK) {
    __shared__ int cur[512];
    int t = threadIdx.x, blk = blockIdx.x;
    for (int b = t; b < NBK; b += 256) cur[b] = hist[blk * NBK + b] + bbase[b];
    __syncthreads();
    int chunk = (E + PB - 1) / PB;
    int beg = blk * chunk, end = min(beg + chunk, E);
    for (int e = beg + t; e < end; e += 256) {
        int d = dst[e], sidx = src[e];
        int p = atomicAdd(&cur[d >> 8], 1);
        bucketArr[p] = ((unsigned)sidx << 8) | (unsigned)(d & 255);
    }
}

// one block per bucket: LDS count -> scan -> place. Emits CSR eidx + meta{beg,deg,dinv}.
__global__ __launch_bounds__(256) void k_binsort(const unsigned* __restrict__ bucketArr,
                                                 const int* __restrict__ bbase,
                                                 int* __restrict__ eidx, int4* __restrict__ meta, int N) {
    __shared__ unsigned ledge[LEDGE];
    __shared__ int lcnt[256], lofs[256], lcur[256], lscan[256];
    int b = blockIdx.x, t = threadIdx.x;
    int gb = bbase[b];
    int count = min(bbase[b + 1] - gb, LEDGE);
    for (int j = t; j < count; j += 256) ledge[j] = bucketArr[gb + j];
    lcnt[t] = 0;
    __syncthreads();
    for (int j = t; j < count; j += 256) atomicAdd(&lcnt[ledge[j] & 255u], 1);
    __syncthreads();
    int deg = lcnt[t];
    lscan[t] = deg;
    __syncthreads();
    for (int off = 1; off < 256; off <<= 1) {
        int u = (t >= off) ? lscan[t - off] : 0;
        __syncthreads();
        lscan[t] += u;
        __syncthreads();
    }
    lofs[t] = lscan[t] - deg;  // exclusive
    lcur[t] = 0;
    int node = (b << 8) + t;
    if (node < N) meta[node] = make_int4(gb + lofs[t], deg, __float_as_int(rsqrtf((float)deg + 1.0f)), 0);
    __syncthreads();
    for (int j = t; j < count; j += 256) {
        unsigned v = ledge[j];
        int loc = (int)(v & 255u);
        int p = atomicAdd(&lcur[loc], 1);
        eidx[gb + lofs[loc] + p] = (int)(v >> 8);  // single-writer 16KB window
    }
}

// xbf = bf16(x * dinv), 4 channels per thread
__global__ void k_prescale(const float4* __restrict__ x4, const int4* __restrict__ meta,
                           ushort4* __restrict__ xbf4, int total4) {
    int idx = blockIdx.x * blockDim.x + threadIdx.x;
    if (idx < total4) {
        float di = __int_as_float(meta[idx >> 4].z);
        float4 v = x4[idx];
        ushort4 o;
        o.x = f2bf(v.x * di); o.y = f2bf(v.y * di); o.z = f2bf(v.z * di); o.w = f2bf(v.w * di);
        xbf4[idx] = o;
    }
}

// conv1: t1 = bf16( dinv_i * (sum_nbr xbf[s] + xbf[i]) ). wave = 4 nodes x 16 lanes x 4ch.
// vbuf[32] burst + sched_barrier: all loads issue before any accumulate.
__global__ __launch_bounds__(256, 4) void k_conv1agg(const unsigned short* __restrict__ xbf,
                                                     const int4* __restrict__ meta,
                                                     const int* __restrict__ eidx,
                                                     unsigned short* __restrict__ t1, int N, int Em1) {
    const ushort4* xb4 = (const ushort4*)xbf;
    int tid = threadIdx.x, wave = tid >> 6, lane = tid & 63;
    int g = lane >> 4, gl = lane & 15, gbase = lane & 48;
    for (int i0 = (blockIdx.x * 4 + wave) * 4; i0 < N; i0 += gridDim.x * 16) {
        int i = i0 + g;
        int iclamp = min(i, N - 1);
        int4 m = meta[iclamp];
        int beg = m.x;
        int dcnt = (i < N) ? m.y : 0;
        float di = __int_as_float(m.z);
        int ss0 = eidx[min(beg + gl, Em1)];
        int ss1 = eidx[min(beg + 16 + gl, Em1)];
        ushort4 self = xb4[(size_t)iclamp * 16 + gl];
        ushort4 vbuf[32];
#pragma unroll
        for (int k = 0; k < 32; k++) {
            int sv = __shfl((k < 16) ? ss0 : ss1, gbase + (k & 15), 64);
            sv = (k < dcnt) ? sv : iclamp;  // invalid slot -> own row (hot line)
            vbuf[k] = xb4[(size_t)sv * 16 + gl];
        }
        __builtin_amdgcn_sched_barrier(0);  // pin: full burst before first use
        float4 a0 = make_float4(bf2f(self.x), bf2f(self.y), bf2f(self.z), bf2f(self.w));
        float4 a1 = make_float4(0.f, 0.f, 0.f, 0.f), a2 = a1, a3 = a1;
#pragma unroll
        for (int k = 0; k < 32; k++) {
            if (k < dcnt) {
                ushort4 v = vbuf[k];
                float4* a = (k & 3) == 0 ? &a0 : (k & 3) == 1 ? &a1 : (k & 3) == 2 ? &a2 : &a3;
                a->x += bf2f(v.x); a->y += bf2f(v.y); a->z += bf2f(v.z); a->w += bf2f(v.w);
            }
        }
        for (int base = 32; base < dcnt; base += 16) {  // rare tail
            int j = base + gl;
            int ss = eidx[min(beg + j, Em1)];
            int cnt = min(dcnt - base, 16);
#pragma unroll
            for (int k = 0; k < 16; k++) {
                if (k < cnt) {
                    int sv = __shfl(ss, gbase + k, 64);
                    ushort4 v = xb4[(size_t)sv * 16 + gl];
                    float4* a = (k & 3) == 0 ? &a0 : (k & 3) == 1 ? &a1 : (k & 3) == 2 ? &a2 : &a3;
                    a->x += bf2f(v.x); a->y += bf2f(v.y); a->z += bf2f(v.z); a->w += bf2f(v.w);
                }
            }
        }
        if (i < N) {
            ushort4 o;
            o.x = f2bf((a0.x + a1.x + a2.x + a3.x) * di);
            o.y = f2bf((a0.y + a1.y + a2.y + a3.y) * di);
            o.z = f2bf((a0.z + a1.z + a2.z + a3.z) * di);
            o.w = f2bf((a0.w + a1.w + a2.w + a3.w) * di);
            ((ushort4*)t1)[(size_t)i * 16 + gl] = o;
        }
    }
}

// dense per-node dual GEMM: z2 = bf16( (ReLU(gs*(t1@W1)+bias1)*dinv) @ w2l2 )
__global__ __launch_bounds__(256, 2) void k_z(const unsigned short* __restrict__ t1,
                                              const int4* __restrict__ meta,
                                              const float* __restrict__ W1, const float* __restrict__ b1,
                                              const float* __restrict__ gamma, const float* __restrict__ beta,
                                              const float* __restrict__ w2l2, unsigned short* __restrict__ z2, int N) {
    __shared__ __align__(16) float tb[4][F];
    __shared__ __align__(16) float hb[4][F];
    int tid = threadIdx.x, wave = tid >> 6, lane = tid & 63, cc = lane & 31;
    float gs = gamma[lane] * BN_INV;
    float bias1 = fmaf(b1[lane], gs, beta[lane]);
    float w1reg[F], w2reg[F];
#pragma unroll
    for (int k = 0; k < F; k++) w1reg[k] = W1[k * F + lane] * gs;
#pragma unroll
    for (int k = 0; k < F; k++) w2reg[k] = w2l2[k * OUTF + cc];

    for (int r = blockIdx.x * 4 + wave; r < N; r += gridDim.x * 4) {
        float di = __int_as_float(meta[r].z);
        tb[wave][lane] = bf2f(t1[(size_t)r * F + lane]);
        float o = bias1;
        const float4* t4 = (const float4*)tb[wave];
#pragma unroll
        for (int k4 = 0; k4 < 16; k4++) {
            float4 tv = t4[k4];  // broadcast
            o = fmaf(tv.x, w1reg[4 * k4 + 0], o);
            o = fmaf(tv.y, w1reg[4 * k4 + 1], o);
            o = fmaf(tv.z, w1reg[4 * k4 + 2], o);
            o = fmaf(tv.w, w1reg[4 * k4 + 3], o);
        }
        hb[wave][lane] = fmaxf(o, 0.0f) * di;  // h row
        float z = 0.0f;
        const float4* h4 = (const float4*)hb[wave];
#pragma unroll
        for (int k4 = 0; k4 < 16; k4++) {
            float4 hv = h4[k4];
            z = fmaf(hv.x, w2reg[4 * k4 + 0], z);
            z = fmaf(hv.y, w2reg[4 * k4 + 1], z);
            z = fmaf(hv.z, w2reg[4 * k4 + 2], z);
            z = fmaf(hv.w, w2reg[4 * k4 + 3], z);
        }
        if (lane < 32) z2[(size_t)r * OUTF + lane] = f2bf(z);
    }
}

// conv2: slim gather of bf16 z2 (64 B rows). wave = 8 nodes x 8 lanes x 4ch.
// vbuf[24] burst + sched_barrier; logits stored bf16; fused softmax/entropy head.
__global__ __launch_bounds__(256, 4) void k_conv2agg(const unsigned short* __restrict__ z2,
                                                     const int4* __restrict__ meta,
                                                     const int* __restrict__ eidx, const float* __restrict__ b2l2,
                                                     unsigned short* __restrict__ logits_bf, float* __restrict__ wraw,
                                                     unsigned* __restrict__ redmm, int N, int Em1) {
    __shared__ float smn[4], smx[4];
    int tid = threadIdx.x, wave = tid >> 6, lane = tid & 63;
    int g = lane >> 3, gl = lane & 7, gbase = lane & 56;
    float4 bvec = ((const float4*)b2l2)[gl];
    float mn = INFINITY, mx = -INFINITY;
    for (int i0 = (blockIdx.x * 4 + wave) * 8; i0 < N; i0 += gridDim.x * 32) {
        int i = i0 + g;
        int iclamp = min(i, N - 1);
        int4 m = meta[iclamp];
        int beg = m.x;
        int dcnt = (i < N) ? m.y : 0;
        float di = __int_as_float(m.z);
        int ss0 = eidx[min(beg + gl, Em1)];
        int ss1 = eidx[min(beg + 8 + gl, Em1)];
        int ss2 = eidx[min(beg + 16 + gl, Em1)];
        ushort4 self = ((const ushort4*)(z2 + (size_t)iclamp * OUTF))[gl];
        ushort4 vbuf[24];
#pragma unroll
        for (int k = 0; k < 24; k++) {
            int sv = __shfl((k < 8) ? ss0 : (k < 16) ? ss1 : ss2, gbase + (k & 7), 64);
            sv = (k < dcnt) ? sv : iclamp;  // invalid slot -> own row (hot line)
            vbuf[k] = ((const ushort4*)(z2 + (size_t)sv * OUTF))[gl];
        }
        __builtin_amdgcn_sched_barrier(0);  // pin: full burst before first use
        float4 a0 = make_float4(bf2f(self.x), bf2f(self.y), bf2f(self.z), bf2f(self.w));
        if (i >= N) a0 = make_float4(0.f, 0.f, 0.f, 0.f);
        float4 a1 = make_float4(0.f, 0.f, 0.f, 0.f), a2 = a1, a3 = a1;
#pragma unroll
        for (int k = 0; k < 24; k++) {
            if (k < dcnt) {
                ushort4 v = vbuf[k];
                float4* a = (k & 3) == 0 ? &a0 : (k & 3) == 1 ? &a1 : (k & 3) == 2 ? &a2 : &a3;
                a->x += bf2f(v.x); a->y += bf2f(v.y); a->z += bf2f(v.z); a->w += bf2f(v.w);
            }
        }
        for (int base = 24; base < dcnt; base += 8) {  // rare tail
            int j = base + gl;
            int ss = eidx[min(beg + j, Em1)];
            int cnt = min(dcnt - base, 8);
#pragma unroll
            for (int k = 0; k < 8; k++) {
                if (k < cnt) {
                    int sv = __shfl(ss, gbase + k, 64);
                    ushort4 v = ((const ushort4*)(z2 + (size_t)sv * OUTF))[gl];
                    float4* a = (k & 3) == 0 ? &a0 : (k & 3) == 1 ? &a1 : (k & 3) == 2 ? &a2 : &a3;
                    a->x += bf2f(v.x); a->y += bf2f(v.y); a->z += bf2f(v.z); a->w += bf2f(v.w);
                }
            }
        }
        float4 lg;
        lg.x = fmaf(a0.x + a1.x + a2.x + a3.x, di, bvec.x);
        lg.y = fmaf(a0.y + a1.y + a2.y + a3.y, di, bvec.y);
        lg.z = fmaf(a0.z + a1.z + a2.z + a3.z, di, bvec.z);
        lg.w = fmaf(a0.w + a1.w + a2.w + a3.w, di, bvec.w);
        if (i < N) {
            ushort4 ob;
            ob.x = f2bf(lg.x); ob.y = f2bf(lg.y); ob.z = f2bf(lg.z); ob.w = f2bf(lg.w);
            ((ushort4*)(logits_bf + (size_t)i * OUTF))[gl] = ob;
        }
        // softmax + entropy over 32 logits spread across 8 lanes x 4
        float m4 = fmaxf(fmaxf(lg.x, lg.y), fmaxf(lg.z, lg.w));
        for (int off = 4; off > 0; off >>= 1) m4 = fmaxf(m4, __shfl_xor(m4, off, 8));
        float p0 = expf(lg.x - m4), p1 = expf(lg.y - m4), p2 = expf(lg.z - m4), p3 = expf(lg.w - m4);
        float s4 = p0 + p1 + p2 + p3;
        for (int off = 4; off > 0; off >>= 1) s4 += __shfl_xor(s4, off, 8);
        float inv = 1.0f / s4;
        float t0 = p0 * inv, t1v = p1 * inv, t2v = p2 * inv, t3 = p3 * inv;
        float e4 = t0 * logf(t0 + 1e-9f) + t1v * logf(t1v + 1e-9f) + t2v * logf(t2v + 1e-9f) + t3 * logf(t3 + 1e-9f);
        for (int off = 4; off > 0; off >>= 1) e4 += __shfl_xor(e4, off, 8);
        float w = 1.0f / (-e4 + 1e-10f);
        if (i < N) {
            if (gl == 0) wraw[i] = w;
            mn = fminf(mn, w);
            mx = fmaxf(mx, w);
        }
    }
    for (int off = 32; off > 0; off >>= 1) {
        mn = fminf(mn, __shfl_xor(mn, off, 64));
        mx = fmaxf(mx, __shfl_xor(mx, off, 64));
    }
    if (lane == 0) { smn[wave] = mn; smx[wave] = mx; }
    __syncthreads();
    if (tid == 0) {
        float a = fminf(fminf(smn[0], smn[1]), fminf(smn[2], smn[3]));
        float b = fmaxf(fmaxf(smx[0], smx[1]), fmaxf(smx[2], smx[3]));
        atomicMin(&redmm[33], fenc(a));
        atomicMax(&redmm[34], fenc(b));
    }
}

__global__ __launch_bounds__(256) void k_weight(const unsigned short* __restrict__ logits_bf,
                                                const float* __restrict__ wraw,
                                                float* __restrict__ red, int N) {
    const unsigned* mm = (const unsigned*)red;
    float mn = fdec(mm[33]), mx = fdec(mm[34]);
    float inv = 1.0f / (mx - mn);
    int c = threadIdx.x & 31;
    int g = threadIdx.x >> 5;  // 8 row-groups
    float acc = 0.0f, es = 0.0f;
    for (int r = blockIdx.x * 8 + g; r < N; r += gridDim.x * 8) {
        float e = expf((wraw[r] - mn) * inv);
        acc += e * bf2f(logits_bf[(size_t)r * OUTF + c]);
        if (c == 0) es += e;
    }
    __shared__ float sa[8][OUTF];
    __shared__ float se[8];
    sa[g][c] = acc;
    if (c == 0) se[g] = es;
    __syncthreads();
    if (g == 0) {
        float t = sa[0][c];
#pragma unroll
        for (int i = 1; i < 8; i++) t += sa[i][c];
        unsafeAtomicAdd(&red[c], t);
        if (c == 0) {
            float u = 0.0f;
#pragma unroll
            for (int i = 0; i < 8; i++) u += se[i];
            unsafeAtomicAdd(&red[32], u);
        }
    }
}

__global__ void k_final(const float* __restrict__ red, const float* __restrict__ w3,
                        const float* __restrict__ b3, float* __restrict__ out) {
    int j = threadIdx.x;  // 64 threads
    float s = red[32];
    float o = b3[j];
#pragma unroll
    for (int cc = 0; cc < OUTF; cc++) o += (red[cc] / s) * w3[cc * F + j];
    out[j] = o;
}

extern "C" void kernel_launch(void* const* d_in, const int* in_sizes, int n_in,
                              void* d_out, int out_size, void* d_ws, size_t ws_size,
                              hipStream_t stream) {
    const float* x     = (const float*)d_in[0];
    const int*   ei    = (const int*)d_in[1];
    const float* W1    = (const float*)d_in[2];
    const float* b1    = (const float*)d_in[3];
    const float* gamma = (const float*)d_in[4];
    const float* beta  = (const float*)d_in[5];
    const float* W2    = (const float*)d_in[6];
    const float* b2    = (const float*)d_in[7];
    const float* l2w   = (const float*)d_in[8];
    const float* l2b   = (const float*)d_in[9];
    const float* l3w   = (const float*)d_in[10];
    const float* l3b   = (const float*)d_in[11];

    int N = in_sizes[0] / F;
    int E = in_sizes[1] / 2;
    const int* src = ei;
    const int* dst = ei + E;
    int NBK = (N + 255) >> 8;  // 391 buckets of 256 nodes (<=512 assumed)

    // workspace layout (16B-aligned chunks)
    char* p = (char*)d_ws;
    int* hist = (int*)p;                p += (size_t)PB * NBK * 4;
    int* btot = (int*)p;                p += 512 * 4;
    int* bbase = (int*)p;               p += 516 * 4;
    unsigned* bucketArr = (unsigned*)p; p += (size_t)E * 4;
    int4* meta = (int4*)p;              p += (size_t)N * 16;
    int* eidx = (int*)p;                p += (size_t)E * 4;
    float* red = (float*)p;             p += 64 * 4;
    float* w2l2 = (float*)p;            p += F * OUTF * 4;
    float* b2l2 = (float*)p;            p += OUTF * 4 + 32;
    unsigned short* xbf = (unsigned short*)p;  p += (size_t)N * F * 2;  // aliased by z2
    unsigned short* t1 = (unsigned short*)p;   p += (size_t)N * F * 2;  // aliased by logits
    float* wraw = (float*)p;            p += (size_t)N * 4;
    unsigned short* z2 = xbf;                  // xbf dead after conv1agg
    unsigned short* logits_bf = t1;            // t1 dead after k_z

    // setup + privatized counting-sort CSR build
    k_fuse<<<8, 256, 0, stream>>>(W2, b2, l2w, l2b, w2l2, b2l2, red);
    k_hist<<<PB, 256, 0, stream>>>(dst, hist, E, NBK);
    k_hscan1<<<NBK, PB, 0, stream>>>(hist, btot, NBK);
    k_hscan2<<<1, 512, 0, stream>>>(btot, bbase, NBK);
    k_place<<<PB, 256, 0, stream>>>(src, dst, hist, bbase, bucketArr, E, NBK);
    k_binsort<<<NBK, 256, 0, stream>>>(bucketArr, bbase, eidx, meta, N);
    k_prescale<<<(N * 16 + 255) / 256, 256, 0, stream>>>((const float4*)x, meta, (ushort4*)xbf, N * 16);

    // convs
    k_conv1agg<<<2048, 256, 0, stream>>>(xbf, meta, eidx, t1, N, E - 1);
    k_z<<<1024, 256, 0, stream>>>(t1, meta, W1, b1, gamma, beta, w2l2, z2, N);
    k_conv2agg<<<2048, 256, 0, stream>>>(z2, meta, eidx, b2l2, logits_bf, wraw, (unsigned*)red, N, E - 1);

    // pooling head
    k_weight<<<1024, 256, 0, stream>>>(logits_bf, wraw, red, N);
    k_final<<<1, 64, 0, stream>>>(red, l3w, l3b, (float*)d_out);
}

// Round 13
// 331.404 us; speedup vs baseline: 1.2044x; 1.0826x over previous
//
#include <hip/hip_runtime.h>
#include <hip/hip_bf16.h>
#include <hip/hip_fp8.h>
#include <math.h>

// GCN. CSR via block-privatized 2-pass counting sort (single-writer lines).
// r13: gathered arrays in OCP fp8-e4m3 (HW cvt) — xq rows 64B (6.4MB), z2q
// rows 32B (3.2MB < 4MB per-XCD L2 -> resident). r12 arithmetic: conv2agg at
// 0.9 miss-req/cyc/XCD = L2 miss-issue ceiling; only fewer misses help.
// Scales: xq = fp8(x*dinv*32), z2q = fp8(z*64); 1/scale folded into di.

#define F 64
#define OUTF 32
#define PB 128            // edge-partition blocks (privatized sort)
#define LEDGE 5632        // per-bucket LDS capacity (mean 4096)
#define BN_INV 0.9999950000374997f  // rsqrt(1 + 1e-5)
#define ESC_X 32.0f
#define IESC_X 0.03125f
#define ESC_Z 64.0f
#define IESC_Z 0.015625f

__device__ __forceinline__ unsigned fenc(float f) {
    unsigned u = __float_as_uint(f);
    return (u & 0x80000000u) ? ~u : (u | 0x80000000u);
}
__device__ __forceinline__ float fdec(unsigned e) {
    return (e & 0x80000000u) ? __uint_as_float(e & 0x7fffffffu) : __uint_as_float(~e);
}
__device__ __forceinline__ unsigned short f2bf(float f) {  // RNE
    unsigned u = __float_as_uint(f);
    return (unsigned short)((u + 0x7fffu + ((u >> 16) & 1u)) >> 16);
}
__device__ __forceinline__ float bf2f(unsigned short h) {
    return __uint_as_float((unsigned)h << 16);
}

#if __has_builtin(__builtin_amdgcn_cvt_f32_fp8) && __has_builtin(__builtin_amdgcn_cvt_pk_fp8_f32)
__device__ __forceinline__ float4 fp8x4(unsigned v) {
    return make_float4(__builtin_amdgcn_cvt_f32_fp8((int)v, 0),
                       __builtin_amdgcn_cvt_f32_fp8((int)v, 1),
                       __builtin_amdgcn_cvt_f32_fp8((int)v, 2),
                       __builtin_amdgcn_cvt_f32_fp8((int)v, 3));
}
__device__ __forceinline__ unsigned fp8pk4(float a, float b, float c, float d) {
    int r = __builtin_amdgcn_cvt_pk_fp8_f32(a, b, 0, false);
    r = __builtin_amdgcn_cvt_pk_fp8_f32(c, d, r, true);
    return (unsigned)r;
}
__device__ __forceinline__ unsigned char fp8enc1(float a) {
    return (unsigned char)(__builtin_amdgcn_cvt_pk_fp8_f32(a, a, 0, false) & 0xff);
}
#else
__device__ __forceinline__ float fp8d1(unsigned char b) {
    __hip_fp8_e4m3 v; v.__x = (__hip_fp8_storage_t)b; return (float)v;
}
__device__ __forceinline__ float4 fp8x4(unsigned v) {
    return make_float4(fp8d1(v & 255u), fp8d1((v >> 8) & 255u), fp8d1((v >> 16) & 255u), fp8d1((v >> 24) & 255u));
}
__device__ __forceinline__ unsigned char fp8enc1(float a) {
    return (unsigned char)__hip_fp8_e4m3(a).__x;
}
__device__ __forceinline__ unsigned fp8pk4(float a, float b, float c, float d) {
    return (unsigned)fp8enc1(a) | ((unsigned)fp8enc1(b) << 8) | ((unsigned)fp8enc1(c) << 16) | ((unsigned)fp8enc1(d) << 24);
}
#endif

// red layout: [0..31] acc_c, [32] esum, [33] min-enc(uint), [34] max-enc(uint)

__global__ void k_fuse(const float* __restrict__ W2, const float* __restrict__ b2,
                       const float* __restrict__ l2w, const float* __restrict__ l2b,
                       float* __restrict__ w2l2, float* __restrict__ b2l2, float* __restrict__ red) {
    int t = blockIdx.x * blockDim.x + threadIdx.x;  // 2048 threads
    int k = t >> 5, cc = t & 31;
    float o = 0.0f;
    for (int j = 0; j < F; j++) o += W2[k * F + j] * l2w[j * OUTF + cc];
    w2l2[k * OUTF + cc] = o;
    if (t < OUTF) {
        float b = l2b[t];
        for (int j = 0; j < F; j++) b += b2[j] * l2w[j * OUTF + t];
        b2l2[t] = b;
    }
    if (t < 33) red[t] = 0.0f;
    if (t == 33) ((unsigned*)red)[33] = 0xFFFFFFFFu;
    if (t == 34) ((unsigned*)red)[34] = 0u;
}

// pass 1: per-block LDS histogram of dst>>8 over this block's private chunk
__global__ __launch_bounds__(256) void k_hist(const int* __restrict__ dst, int* __restrict__ hist,
                                              int E, int NBK) {
    __shared__ int lh[512];
    int t = threadIdx.x, blk = blockIdx.x;
    for (int b = t; b < NBK; b += 256) lh[b] = 0;
    __syncthreads();
    int chunk = (E + PB - 1) / PB;
    int beg = blk * chunk, end = min(beg + chunk, E);
    for (int e = beg + t; e < end; e += 256) atomicAdd(&lh[dst[e] >> 8], 1);
    __syncthreads();
    for (int b = t; b < NBK; b += 256) hist[blk * NBK + b] = lh[b];  // dense coalesced
}

// per-bucket exclusive scan across the PB blocks (one block per bucket)
__global__ __launch_bounds__(PB) void k_hscan1(int* __restrict__ hist, int* __restrict__ btot, int NBK) {
    __shared__ int s[PB];
    int b = blockIdx.x, t = threadIdx.x;
    int v = hist[t * NBK + b];
    s[t] = v;
    __syncthreads();
    for (int off = 1; off < PB; off <<= 1) {
        int u = (t >= off) ? s[t - off] : 0;
        __syncthreads();
        s[t] += u;
        __syncthreads();
    }
    hist[t * NBK + b] = s[t] - v;  // exclusive within bucket
    if (t == PB - 1) btot[b] = s[t];
}

// scan bucket totals -> bbase (1 block; NBK <= 512)
__global__ void k_hscan2(const int* __restrict__ btot, int* __restrict__ bbase, int NBK) {
    __shared__ int s[512];
    int t = threadIdx.x;
    int v = (t < NBK) ? btot[t] : 0;
    s[t] = v;
    __syncthreads();
    for (int off = 1; off < 512; off <<= 1) {
        int u = (t >= off) ? s[t - off] : 0;
        __syncthreads();
        s[t] += u;
        __syncthreads();
    }
    if (t < NBK) {
        bbase[t] = s[t] - v;
        if (t == NBK - 1) bbase[NBK] = s[t];
    }
}

// pass 2: private cursors in LDS (hist offset + bucket base); single-writer lines
__global__ __launch_bounds__(256) void k_place(const int* __restrict__ src, const int* __restrict__ dst,
                                               const int* __restrict__ hist, const int* __restrict__ bbase,
                                               unsigned* __restrict__ bucketArr, int E, int NBK) {
    __shared__ int cur[512];
    int t = threadIdx.x, blk = blockIdx.x;
    for (int b = t; b < NBK; b += 256) cur[b] = hist[blk * NBK + b] + bbase[b];
    __syncthreads();
    int chunk = (E + PB - 1) / PB;
    int beg = blk * chunk, end = min(beg + chunk, E);
    for (int e = beg + t; e < end; e += 256) {
        int d = dst[e], sidx = src[e];
        int p = atomicAdd(&cur[d >> 8], 1);
        bucketArr[p] = ((unsigned)sidx << 8) | (unsigned)(d & 255);
    }
}

// one block per bucket: LDS count -> scan -> place. Emits CSR eidx + meta{beg,deg,dinv}.
__global__ __launch_bounds__(256) void k_binsort(const unsigned* __restrict__ bucketArr,
                                                 const int* __restrict__ bbase,
                                                 int* __restrict__ eidx, int4* __restrict__ meta, int N) {
    __shared__ unsigned ledge[LEDGE];
    __shared__ int lcnt[256], lofs[256], lcur[256], lscan[256];
    int b = blockIdx.x, t = threadIdx.x;
    int gb = bbase[b];
    int count = min(bbase[b + 1] - gb, LEDGE);
    for (int j = t; j < count; j += 256) ledge[j] = bucketArr[gb + j];
    lcnt[t] = 0;
    __syncthreads();
    for (int j = t; j < count; j += 256) atomicAdd(&lcnt[ledge[j] & 255u], 1);
    __syncthreads();
    int deg = lcnt[t];
    lscan[t] = deg;
    __syncthreads();
    for (int off = 1; off < 256; off <<= 1) {
        int u = (t >= off) ? lscan[t - off] : 0;
        __syncthreads();
        lscan[t] += u;
        __syncthreads();
    }
    lofs[t] = lscan[t] - deg;  // exclusive
    lcur[t] = 0;
    int node = (b << 8) + t;
    if (node < N) meta[node] = make_int4(gb + lofs[t], deg, __float_as_int(rsqrtf((float)deg + 1.0f)), 0);
    __syncthreads();
    for (int j = t; j < count; j += 256) {
        unsigned v = ledge[j];
        int loc = (int)(v & 255u);
        int p = atomicAdd(&lcur[loc], 1);
        eidx[gb + lofs[loc] + p] = (int)(v >> 8);  // single-writer 16KB window
    }
}

// xq = fp8(x * dinv * 32): one dword (4 ch) per thread; row = 16 dwords = 64 B
__global__ void k_prescale(const float4* __restrict__ x4, const int4* __restrict__ meta,
                           unsigned* __restrict__ xq, int total4) {
    int idx = blockIdx.x * blockDim.x + threadIdx.x;
    if (idx < total4) {
        float di = __int_as_float(meta[idx >> 4].z) * ESC_X;
        float4 v = x4[idx];
        xq[idx] = fp8pk4(v.x * di, v.y * di, v.z * di, v.w * di);
    }
}

// conv1: t1 = bf16( dinv/32 * (sum_nbr xq[s] + xq[i]) ). wave = 4 nodes x 16 lanes x 4ch.
// vbuf[32] dword burst + sched_barrier.
__global__ __launch_bounds__(256, 4) void k_conv1agg(const unsigned* __restrict__ xq,
                                                     const int4* __restrict__ meta,
                                                     const int* __restrict__ eidx,
                                                     unsigned short* __restrict__ t1, int N, int Em1) {
    int tid = threadIdx.x, wave = tid >> 6, lane = tid & 63;
    int g = lane >> 4, gl = lane & 15, gbase = lane & 48;
    for (int i0 = (blockIdx.x * 4 + wave) * 4; i0 < N; i0 += gridDim.x * 16) {
        int i = i0 + g;
        int iclamp = min(i, N - 1);
        int4 m = meta[iclamp];
        int beg = m.x;
        int dcnt = (i < N) ? m.y : 0;
        float dis = __int_as_float(m.z) * IESC_X;
        int ss0 = eidx[min(beg + gl, Em1)];
        int ss1 = eidx[min(beg + 16 + gl, Em1)];
        unsigned selfv = xq[(size_t)iclamp * 16 + gl];
        unsigned vbuf[32];
#pragma unroll
        for (int k = 0; k < 32; k++) {
            int sv = __shfl((k < 16) ? ss0 : ss1, gbase + (k & 15), 64);
            sv = (k < dcnt) ? sv : iclamp;  // invalid slot -> own row (hot line)
            vbuf[k] = xq[(size_t)sv * 16 + gl];
        }
        __builtin_amdgcn_sched_barrier(0);  // pin: full burst before first use
        float4 a0 = fp8x4(selfv);
        float4 a1 = make_float4(0.f, 0.f, 0.f, 0.f), a2 = a1, a3 = a1;
#pragma unroll
        for (int k = 0; k < 32; k++) {
            if (k < dcnt) {
                float4 v = fp8x4(vbuf[k]);
                float4* a = (k & 3) == 0 ? &a0 : (k & 3) == 1 ? &a1 : (k & 3) == 2 ? &a2 : &a3;
                a->x += v.x; a->y += v.y; a->z += v.z; a->w += v.w;
            }
        }
        for (int base = 32; base < dcnt; base += 16) {  // rare tail
            int j = base + gl;
            int ss = eidx[min(beg + j, Em1)];
            int cnt = min(dcnt - base, 16);
#pragma unroll
            for (int k = 0; k < 16; k++) {
                if (k < cnt) {
                    int sv = __shfl(ss, gbase + k, 64);
                    float4 v = fp8x4(xq[(size_t)sv * 16 + gl]);
                    float4* a = (k & 3) == 0 ? &a0 : (k & 3) == 1 ? &a1 : (k & 3) == 2 ? &a2 : &a3;
                    a->x += v.x; a->y += v.y; a->z += v.z; a->w += v.w;
                }
            }
        }
        if (i < N) {
            ushort4 o;
            o.x = f2bf((a0.x + a1.x + a2.x + a3.x) * dis);
            o.y = f2bf((a0.y + a1.y + a2.y + a3.y) * dis);
            o.z = f2bf((a0.z + a1.z + a2.z + a3.z) * dis);
            o.w = f2bf((a0.w + a1.w + a2.w + a3.w) * dis);
            ((ushort4*)t1)[(size_t)i * 16 + gl] = o;
        }
    }
}

// dense per-node dual GEMM: z2q = fp8(64 * (ReLU(gs*(t1@W1)+bias1)*dinv) @ w2l2)
__global__ __launch_bounds__(256, 2) void k_z(const unsigned short* __restrict__ t1,
                                              const int4* __restrict__ meta,
                                              const float* __restrict__ W1, const float* __restrict__ b1,
                                              const float* __restrict__ gamma, const float* __restrict__ beta,
                                              const float* __restrict__ w2l2, unsigned char* __restrict__ z2q, int N) {
    __shared__ __align__(16) float tb[4][F];
    __shared__ __align__(16) float hb[4][F];
    int tid = threadIdx.x, wave = tid >> 6, lane = tid & 63, cc = lane & 31;
    float gs = gamma[lane] * BN_INV;
    float bias1 = fmaf(b1[lane], gs, beta[lane]);
    float w1reg[F], w2reg[F];
#pragma unroll
    for (int k = 0; k < F; k++) w1reg[k] = W1[k * F + lane] * gs;
#pragma unroll
    for (int k = 0; k < F; k++) w2reg[k] = w2l2[k * OUTF + cc];

    for (int r = blockIdx.x * 4 + wave; r < N; r += gridDim.x * 4) {
        float di = __int_as_float(meta[r].z);
        tb[wave][lane] = bf2f(t1[(size_t)r * F + lane]);
        float o = bias1;
        const float4* t4 = (const float4*)tb[wave];
#pragma unroll
        for (int k4 = 0; k4 < 16; k4++) {
            float4 tv = t4[k4];  // broadcast
            o = fmaf(tv.x, w1reg[4 * k4 + 0], o);
            o = fmaf(tv.y, w1reg[4 * k4 + 1], o);
            o = fmaf(tv.z, w1reg[4 * k4 + 2], o);
            o = fmaf(tv.w, w1reg[4 * k4 + 3], o);
        }
        hb[wave][lane] = fmaxf(o, 0.0f) * di;  // h row
        float z = 0.0f;
        const float4* h4 = (const float4*)hb[wave];
#pragma unroll
        for (int k4 = 0; k4 < 16; k4++) {
            float4 hv = h4[k4];
            z = fmaf(hv.x, w2reg[4 * k4 + 0], z);
            z = fmaf(hv.y, w2reg[4 * k4 + 1], z);
            z = fmaf(hv.z, w2reg[4 * k4 + 2], z);
            z = fmaf(hv.w, w2reg[4 * k4 + 3], z);
        }
        if (lane < 32) z2q[(size_t)r * OUTF + cc] = fp8enc1(z * ESC_Z);
    }
}

// conv2: gather of fp8 z2q (32 B rows, L2-resident). wave = 8 nodes x 8 lanes x 4ch.
// vbuf[24] dword burst + sched_barrier; logits bf16; fused softmax/entropy head.
__global__ __launch_bounds__(256, 4) void k_conv2agg(const unsigned* __restrict__ z2q,
                                                     const int4* __restrict__ meta,
                                                     const int* __restrict__ eidx, const float* __restrict__ b2l2,
                                                     unsigned short* __restrict__ logits_bf, float* __restrict__ wraw,
                                                     unsigned* __restrict__ redmm, int N, int Em1) {
    __shared__ float smn[4], smx[4];
    int tid = threadIdx.x, wave = tid >> 6, lane = tid & 63;
    int g = lane >> 3, gl = lane & 7, gbase = lane & 56;
    float4 bvec = ((const float4*)b2l2)[gl];
    float mn = INFINITY, mx = -INFINITY;
    for (int i0 = (blockIdx.x * 4 + wave) * 8; i0 < N; i0 += gridDim.x * 32) {
        int i = i0 + g;
        int iclamp = min(i, N - 1);
        int4 m = meta[iclamp];
        int beg = m.x;
        int dcnt = (i < N) ? m.y : 0;
        float dis = __int_as_float(m.z) * IESC_Z;
        int ss0 = eidx[min(beg + gl, Em1)];
        int ss1 = eidx[min(beg + 8 + gl, Em1)];
        int ss2 = eidx[min(beg + 16 + gl, Em1)];
        unsigned selfv = z2q[(size_t)iclamp * 8 + gl];
        unsigned vbuf[24];
#pragma unroll
        for (int k = 0; k < 24; k++) {
            int sv = __shfl((k < 8) ? ss0 : (k < 16) ? ss1 : ss2, gbase + (k & 7), 64);
            sv = (k < dcnt) ? sv : iclamp;  // invalid slot -> own row (hot line)
            vbuf[k] = z2q[(size_t)sv * 8 + gl];
        }
        __builtin_amdgcn_sched_barrier(0);  // pin: full burst before first use
        float4 a0 = fp8x4(selfv);
        if (i >= N) a0 = make_float4(0.f, 0.f, 0.f, 0.f);
        float4 a1 = make_float4(0.f, 0.f, 0.f, 0.f), a2 = a1, a3 = a1;
#pragma unroll
        for (int k = 0; k < 24; k++) {
            if (k < dcnt) {
                float4 v = fp8x4(vbuf[k]);
                float4* a = (k & 3) == 0 ? &a0 : (k & 3) == 1 ? &a1 : (k & 3) == 2 ? &a2 : &a3;
                a->x += v.x; a->y += v.y; a->z += v.z; a->w += v.w;
            }
        }
        for (int base = 24; base < dcnt; base += 8) {  // rare tail
            int j = base + gl;
            int ss = eidx[min(beg + j, Em1)];
            int cnt = min(dcnt - base, 8);
#pragma unroll
            for (int k = 0; k < 8; k++) {
                if (k < cnt) {
                    int sv = __shfl(ss, gbase + k, 64);
                    float4 v = fp8x4(z2q[(size_t)sv * 8 + gl]);
                    float4* a = (k & 3) == 0 ? &a0 : (k & 3) == 1 ? &a1 : (k & 3) == 2 ? &a2 : &a3;
                    a->x += v.x; a->y += v.y; a->z += v.z; a->w += v.w;
                }
            }
        }
        float4 lg;
        lg.x = fmaf(a0.x + a1.x + a2.x + a3.x, dis, bvec.x);
        lg.y = fmaf(a0.y + a1.y + a2.y + a3.y, dis, bvec.y);
        lg.z = fmaf(a0.z + a1.z + a2.z + a3.z, dis, bvec.z);
        lg.w = fmaf(a0.w + a1.w + a2.w + a3.w, dis, bvec.w);
        if (i < N) {
            ushort4 ob;
            ob.x = f2bf(lg.x); ob.y = f2bf(lg.y); ob.z = f2bf(lg.z); ob.w = f2bf(lg.w);
            ((ushort4*)(logits_bf + (size_t)i * OUTF))[gl] = ob;
        }
        // softmax + entropy over 32 logits spread across 8 lanes x 4
        float m4 = fmaxf(fmaxf(lg.x, lg.y), fmaxf(lg.z, lg.w));
        for (int off = 4; off > 0; off >>= 1) m4 = fmaxf(m4, __shfl_xor(m4, off, 8));
        float p0 = expf(lg.x - m4), p1 = expf(lg.y - m4), p2 = expf(lg.z - m4), p3 = expf(lg.w - m4);
        float s4 = p0 + p1 + p2 + p3;
        for (int off = 4; off > 0; off >>= 1) s4 += __shfl_xor(s4, off, 8);
        float inv = 1.0f / s4;
        float t0 = p0 * inv, t1v = p1 * inv, t2v = p2 * inv, t3 = p3 * inv;
        float e4 = t0 * logf(t0 + 1e-9f) + t1v * logf(t1v + 1e-9f) + t2v * logf(t2v + 1e-9f) + t3 * logf(t3 + 1e-9f);
        for (int off = 4; off > 0; off >>= 1) e4 += __shfl_xor(e4, off, 8);
        float w = 1.0f / (-e4 + 1e-10f);
        if (i < N) {
            if (gl == 0) wraw[i] = w;
            mn = fminf(mn, w);
            mx = fmaxf(mx, w);
        }
    }
    for (int off = 32; off > 0; off >>= 1) {
        mn = fminf(mn, __shfl_xor(mn, off, 64));
        mx = fmaxf(mx, __shfl_xor(mx, off, 64));
    }
    if (lane == 0) { smn[wave] = mn; smx[wave] = mx; }
    __syncthreads();
    if (tid == 0) {
        float a = fminf(fminf(smn[0], smn[1]), fminf(smn[2], smn[3]));
        float b = fmaxf(fmaxf(smx[0], smx[1]), fmaxf(smx[2], smx[3]));
        atomicMin(&redmm[33], fenc(a));
        atomicMax(&redmm[34], fenc(b));
    }
}

__global__ __launch_bounds__(256) void k_weight(const unsigned short* __restrict__ logits_bf,
                                                const float* __restrict__ wraw,
                                                float* __restrict__ red, int N) {
    const unsigned* mm = (const unsigned*)red;
    float mn = fdec(mm[33]), mx = fdec(mm[34]);
    float inv = 1.0f / (mx - mn);
    int c = threadIdx.x & 31;
    int g = threadIdx.x >> 5;  // 8 row-groups
    float acc = 0.0f, es = 0.0f;
    for (int r = blockIdx.x * 8 + g; r < N; r += gridDim.x * 8) {
        float e = expf((wraw[r] - mn) * inv);
        acc += e * bf2f(logits_bf[(size_t)r * OUTF + c]);
        if (c == 0) es += e;
    }
    __shared__ float sa[8][OUTF];
    __shared__ float se[8];
    sa[g][c] = acc;
    if (c == 0) se[g] = es;
    __syncthreads();
    if (g == 0) {
        float t = sa[0][c];
#pragma unroll
        for (int i = 1; i < 8; i++) t += sa[i][c];
        unsafeAtomicAdd(&red[c], t);
        if (c == 0) {
            float u = 0.0f;
#pragma unroll
            for (int i = 0; i < 8; i++) u += se[i];
            unsafeAtomicAdd(&red[32], u);
        }
    }
}

__global__ void k_final(const float* __restrict__ red, const float* __restrict__ w3,
                        const float* __restrict__ b3, float* __restrict__ out) {
    int j = threadIdx.x;  // 64 threads
    float s = red[32];
    float o = b3[j];
#pragma unroll
    for (int cc = 0; cc < OUTF; cc++) o += (red[cc] / s) * w3[cc * F + j];
    out[j] = o;
}

extern "C" void kernel_launch(void* const* d_in, const int* in_sizes, int n_in,
                              void* d_out, int out_size, void* d_ws, size_t ws_size,
                              hipStream_t stream) {
    const float* x     = (const float*)d_in[0];
    const int*   ei    = (const int*)d_in[1];
    const float* W1    = (const float*)d_in[2];
    const float* b1    = (const float*)d_in[3];
    const float* gamma = (const float*)d_in[4];
    const float* beta  = (const float*)d_in[5];
    const float* W2    = (const float*)d_in[6];
    const float* b2    = (const float*)d_in[7];
    const float* l2w   = (const float*)d_in[8];
    const float* l2b   = (const float*)d_in[9];
    const float* l3w   = (const float*)d_in[10];
    const float* l3b   = (const float*)d_in[11];

    int N = in_sizes[0] / F;
    int E = in_sizes[1] / 2;
    const int* src = ei;
    const int* dst = ei + E;
    int NBK = (N + 255) >> 8;  // 391 buckets of 256 nodes (<=512 assumed)

    // workspace layout (16B-aligned chunks)
    char* p = (char*)d_ws;
    int* hist = (int*)p;                p += (size_t)PB * NBK * 4;
    int* btot = (int*)p;                p += 512 * 4;
    int* bbase = (int*)p;               p += 516 * 4;
    unsigned* bucketArr = (unsigned*)p; p += (size_t)E * 4;
    int4* meta = (int4*)p;              p += (size_t)N * 16;
    int* eidx = (int*)p;                p += (size_t)E * 4;
    float* red = (float*)p;             p += 64 * 4;
    float* w2l2 = (float*)p;            p += F * OUTF * 4;
    float* b2l2 = (float*)p;            p += OUTF * 4 + 32;
    unsigned* xq = (unsigned*)p;        p += (size_t)N * F;      // fp8, 64 B/row (aliased by z2q)
    unsigned short* t1 = (unsigned short*)p; p += (size_t)N * F * 2;  // bf16 (aliased by logits)
    float* wraw = (float*)p;            p += (size_t)N * 4;
    unsigned char* z2q = (unsigned char*)xq;   // xq dead after conv1agg; 32 B/row
    unsigned short* logits_bf = t1;            // t1 dead after k_z

    // setup + privatized counting-sort CSR build
    k_fuse<<<8, 256, 0, stream>>>(W2, b2, l2w, l2b, w2l2, b2l2, red);
    k_hist<<<PB, 256, 0, stream>>>(dst, hist, E, NBK);
    k_hscan1<<<NBK, PB, 0, stream>>>(hist, btot, NBK);
    k_hscan2<<<1, 512, 0, stream>>>(btot, bbase, NBK);
    k_place<<<PB, 256, 0, stream>>>(src, dst, hist, bbase, bucketArr, E, NBK);
    k_binsort<<<NBK, 256, 0, stream>>>(bucketArr, bbase, eidx, meta, N);
    k_prescale<<<(N * 16 + 255) / 256, 256, 0, stream>>>((const float4*)x, meta, xq, N * 16);

    // convs
    k_conv1agg<<<2048, 256, 0, stream>>>(xq, meta, eidx, t1, N, E - 1);
    k_z<<<1024, 256, 0, stream>>>(t1, meta, W1, b1, gamma, beta, w2l2, z2q, N);
    k_conv2agg<<<2048, 256, 0, stream>>>((const unsigned*)z2q, meta, eidx, b2l2, logits_bf, wraw, (unsigned*)red, N, E - 1);

    // pooling head
    k_weight<<<1024, 256, 0, stream>>>(logits_bf, wraw, red, N);
    k_final<<<1, 64, 0, stream>>>(red, l3w, l3b, (float*)d_out);
}

// Round 14
// 325.359 us; speedup vs baseline: 1.2268x; 1.0186x over previous
//
#include <hip/hip_runtime.h>
#include <hip/hip_bf16.h>
#include <hip/hip_fp8.h>
#include <math.h>

// GCN. CSR via block-privatized 2-pass counting sort; fp8-e4m3 gathered arrays
// (xq 64B rows, z2q 32B rows — L2-resident). r14: k_z de-LDS'd — r13 PMC showed
// it LDS-pipe bound (34 ds_read_b128/row = 408 cyc/row = 62us). Now: t row via
// global broadcast loads (t1 f32, all lanes same addr), GEMM2 half-split
// (lanes 0-31/32-63 reduce half the k-range each + shfl_xor combine), h staged
// bf16 -> ~6 LDS ops/row.

#define F 64
#define OUTF 32
#define PB 128            // edge-partition blocks (privatized sort)
#define LEDGE 5632        // per-bucket LDS capacity (mean 4096)
#define BN_INV 0.9999950000374997f  // rsqrt(1 + 1e-5)
#define ESC_X 32.0f
#define IESC_X 0.03125f
#define ESC_Z 64.0f
#define IESC_Z 0.015625f

__device__ __forceinline__ unsigned fenc(float f) {
    unsigned u = __float_as_uint(f);
    return (u & 0x80000000u) ? ~u : (u | 0x80000000u);
}
__device__ __forceinline__ float fdec(unsigned e) {
    return (e & 0x80000000u) ? __uint_as_float(e & 0x7fffffffu) : __uint_as_float(~e);
}
__device__ __forceinline__ unsigned short f2bf(float f) {  // RNE
    unsigned u = __float_as_uint(f);
    return (unsigned short)((u + 0x7fffu + ((u >> 16) & 1u)) >> 16);
}
__device__ __forceinline__ float bf2f(unsigned short h) {
    return __uint_as_float((unsigned)h << 16);
}

#if __has_builtin(__builtin_amdgcn_cvt_f32_fp8) && __has_builtin(__builtin_amdgcn_cvt_pk_fp8_f32)
__device__ __forceinline__ float4 fp8x4(unsigned v) {
    return make_float4(__builtin_amdgcn_cvt_f32_fp8((int)v, 0),
                       __builtin_amdgcn_cvt_f32_fp8((int)v, 1),
                       __builtin_amdgcn_cvt_f32_fp8((int)v, 2),
                       __builtin_amdgcn_cvt_f32_fp8((int)v, 3));
}
__device__ __forceinline__ unsigned fp8pk4(float a, float b, float c, float d) {
    int r = __builtin_amdgcn_cvt_pk_fp8_f32(a, b, 0, false);
    r = __builtin_amdgcn_cvt_pk_fp8_f32(c, d, r, true);
    return (unsigned)r;
}
__device__ __forceinline__ unsigned char fp8enc1(float a) {
    return (unsigned char)(__builtin_amdgcn_cvt_pk_fp8_f32(a, a, 0, false) & 0xff);
}
#else
__device__ __forceinline__ float fp8d1(unsigned char b) {
    __hip_fp8_e4m3 v; v.__x = (__hip_fp8_storage_t)b; return (float)v;
}
__device__ __forceinline__ float4 fp8x4(unsigned v) {
    return make_float4(fp8d1(v & 255u), fp8d1((v >> 8) & 255u), fp8d1((v >> 16) & 255u), fp8d1((v >> 24) & 255u));
}
__device__ __forceinline__ unsigned char fp8enc1(float a) {
    return (unsigned char)__hip_fp8_e4m3(a).__x;
}
__device__ __forceinline__ unsigned fp8pk4(float a, float b, float c, float d) {
    return (unsigned)fp8enc1(a) | ((unsigned)fp8enc1(b) << 8) | ((unsigned)fp8enc1(c) << 16) | ((unsigned)fp8enc1(d) << 24);
}
#endif

// red layout: [0..31] acc_c, [32] esum, [33] min-enc(uint), [34] max-enc(uint)

__global__ void k_fuse(const float* __restrict__ W2, const float* __restrict__ b2,
                       const float* __restrict__ l2w, const float* __restrict__ l2b,
                       float* __restrict__ w2l2, float* __restrict__ b2l2, float* __restrict__ red) {
    int t = blockIdx.x * blockDim.x + threadIdx.x;  // 2048 threads
    int k = t >> 5, cc = t & 31;
    float o = 0.0f;
    for (int j = 0; j < F; j++) o += W2[k * F + j] * l2w[j * OUTF + cc];
    w2l2[k * OUTF + cc] = o;
    if (t < OUTF) {
        float b = l2b[t];
        for (int j = 0; j < F; j++) b += b2[j] * l2w[j * OUTF + t];
        b2l2[t] = b;
    }
    if (t < 33) red[t] = 0.0f;
    if (t == 33) ((unsigned*)red)[33] = 0xFFFFFFFFu;
    if (t == 34) ((unsigned*)red)[34] = 0u;
}

// pass 1: per-block LDS histogram of dst>>8 over this block's private chunk
__global__ __launch_bounds__(256) void k_hist(const int* __restrict__ dst, int* __restrict__ hist,
                                              int E, int NBK) {
    __shared__ int lh[512];
    int t = threadIdx.x, blk = blockIdx.x;
    for (int b = t; b < NBK; b += 256) lh[b] = 0;
    __syncthreads();
    int chunk = (E + PB - 1) / PB;
    int beg = blk * chunk, end = min(beg + chunk, E);
    for (int e = beg + t; e < end; e += 256) atomicAdd(&lh[dst[e] >> 8], 1);
    __syncthreads();
    for (int b = t; b < NBK; b += 256) hist[blk * NBK + b] = lh[b];  // dense coalesced
}

// per-bucket exclusive scan across the PB blocks (one block per bucket)
__global__ __launch_bounds__(PB) void k_hscan1(int* __restrict__ hist, int* __restrict__ btot, int NBK) {
    __shared__ int s[PB];
    int b = blockIdx.x, t = threadIdx.x;
    int v = hist[t * NBK + b];
    s[t] = v;
    __syncthreads();
    for (int off = 1; off < PB; off <<= 1) {
        int u = (t >= off) ? s[t - off] : 0;
        __syncthreads();
        s[t] += u;
        __syncthreads();
    }
    hist[t * NBK + b] = s[t] - v;  // exclusive within bucket
    if (t == PB - 1) btot[b] = s[t];
}

// scan bucket totals -> bbase (1 block; NBK <= 512)
__global__ void k_hscan2(const int* __restrict__ btot, int* __restrict__ bbase, int NBK) {
    __shared__ int s[512];
    int t = threadIdx.x;
    int v = (t < NBK) ? btot[t] : 0;
    s[t] = v;
    __syncthreads();
    for (int off = 1; off < 512; off <<= 1) {
        int u = (t >= off) ? s[t - off] : 0;
        __syncthreads();
        s[t] += u;
        __syncthreads();
    }
    if (t < NBK) {
        bbase[t] = s[t] - v;
        if (t == NBK - 1) bbase[NBK] = s[t];
    }
}

// pass 2: private cursors in LDS (hist offset + bucket base); single-writer lines
__global__ __launch_bounds__(256) void k_place(const int* __restrict__ src, const int* __restrict__ dst,
                                               const int* __restrict__ hist, const int* __restrict__ bbase,
                                               unsigned* __restrict__ bucketArr, int E, int NBK) {
    __shared__ int cur[512];
    int t = threadIdx.x, blk = blockIdx.x;
    for (int b = t; b < NBK; b += 256) cur[b] = hist[blk * NBK + b] + bbase[b];
    __syncthreads();
    int chunk = (E + PB - 1) / PB;
    int beg = blk * chunk, end = min(beg + chunk, E);
    for (int e = beg + t; e < end; e += 256) {
        int d = dst[e], sidx = src[e];
        int p = atomicAdd(&cur[d >> 8], 1);
        bucketArr[p] = ((unsigned)sidx << 8) | (unsigned)(d & 255);
    }
}

// one block per bucket: LDS count -> scan -> place. Emits CSR eidx + meta{beg,deg,dinv}.
__global__ __launch_bounds__(256) void k_binsort(const unsigned* __restrict__ bucketArr,
                                                 const int* __restrict__ bbase,
                                                 int* __restrict__ eidx, int4* __restrict__ meta, int N) {
    __shared__ unsigned ledge[LEDGE];
    __shared__ int lcnt[256], lofs[256], lcur[256], lscan[256];
    int b = blockIdx.x, t = threadIdx.x;
    int gb = bbase[b];
    int count = min(bbase[b + 1] - gb, LEDGE);
    for (int j = t; j < count; j += 256) ledge[j] = bucketArr[gb + j];
    lcnt[t] = 0;
    __syncthreads();
    for (int j = t; j < count; j += 256) atomicAdd(&lcnt[ledge[j] & 255u], 1);
    __syncthreads();
    int deg = lcnt[t];
    lscan[t] = deg;
    __syncthreads();
    for (int off = 1; off < 256; off <<= 1) {
        int u = (t >= off) ? lscan[t - off] : 0;
        __syncthreads();
        lscan[t] += u;
        __syncthreads();
    }
    lofs[t] = lscan[t] - deg;  // exclusive
    lcur[t] = 0;
    int node = (b << 8) + t;
    if (node < N) meta[node] = make_int4(gb + lofs[t], deg, __float_as_int(rsqrtf((float)deg + 1.0f)), 0);
    __syncthreads();
    for (int j = t; j < count; j += 256) {
        unsigned v = ledge[j];
        int loc = (int)(v & 255u);
        int p = atomicAdd(&lcur[loc], 1);
        eidx[gb + lofs[loc] + p] = (int)(v >> 8);  // single-writer 16KB window
    }
}

// xq = fp8(x * dinv * 32): one dword (4 ch) per thread; row = 16 dwords = 64 B
__global__ void k_prescale(const float4* __restrict__ x4, const int4* __restrict__ meta,
                           unsigned* __restrict__ xq, int total4) {
    int idx = blockIdx.x * blockDim.x + threadIdx.x;
    if (idx < total4) {
        float di = __int_as_float(meta[idx >> 4].z) * ESC_X;
        float4 v = x4[idx];
        xq[idx] = fp8pk4(v.x * di, v.y * di, v.z * di, v.w * di);
    }
}

// conv1: t1 = f32( dinv/32 * (sum_nbr xq[s] + xq[i]) ). wave = 4 nodes x 16 lanes x 4ch.
// vbuf[32] dword burst + sched_barrier.
__global__ __launch_bounds__(256, 4) void k_conv1agg(const unsigned* __restrict__ xq,
                                                     const int4* __restrict__ meta,
                                                     const int* __restrict__ eidx,
                                                     float* __restrict__ t1, int N, int Em1) {
    int tid = threadIdx.x, wave = tid >> 6, lane = tid & 63;
    int g = lane >> 4, gl = lane & 15, gbase = lane & 48;
    for (int i0 = (blockIdx.x * 4 + wave) * 4; i0 < N; i0 += gridDim.x * 16) {
        int i = i0 + g;
        int iclamp = min(i, N - 1);
        int4 m = meta[iclamp];
        int beg = m.x;
        int dcnt = (i < N) ? m.y : 0;
        float dis = __int_as_float(m.z) * IESC_X;
        int ss0 = eidx[min(beg + gl, Em1)];
        int ss1 = eidx[min(beg + 16 + gl, Em1)];
        unsigned selfv = xq[(size_t)iclamp * 16 + gl];
        unsigned vbuf[32];
#pragma unroll
        for (int k = 0; k < 32; k++) {
            int sv = __shfl((k < 16) ? ss0 : ss1, gbase + (k & 15), 64);
            sv = (k < dcnt) ? sv : iclamp;  // invalid slot -> own row (hot line)
            vbuf[k] = xq[(size_t)sv * 16 + gl];
        }
        __builtin_amdgcn_sched_barrier(0);  // pin: full burst before first use
        float4 a0 = fp8x4(selfv);
        float4 a1 = make_float4(0.f, 0.f, 0.f, 0.f), a2 = a1, a3 = a1;
#pragma unroll
        for (int k = 0; k < 32; k++) {
            if (k < dcnt) {
                float4 v = fp8x4(vbuf[k]);
                float4* a = (k & 3) == 0 ? &a0 : (k & 3) == 1 ? &a1 : (k & 3) == 2 ? &a2 : &a3;
                a->x += v.x; a->y += v.y; a->z += v.z; a->w += v.w;
            }
        }
        for (int base = 32; base < dcnt; base += 16) {  // rare tail
            int j = base + gl;
            int ss = eidx[min(beg + j, Em1)];
            int cnt = min(dcnt - base, 16);
#pragma unroll
            for (int k = 0; k < 16; k++) {
                if (k < cnt) {
                    int sv = __shfl(ss, gbase + k, 64);
                    float4 v = fp8x4(xq[(size_t)sv * 16 + gl]);
                    float4* a = (k & 3) == 0 ? &a0 : (k & 3) == 1 ? &a1 : (k & 3) == 2 ? &a2 : &a3;
                    a->x += v.x; a->y += v.y; a->z += v.z; a->w += v.w;
                }
            }
        }
        if (i < N) {
            float4 o;
            o.x = (a0.x + a1.x + a2.x + a3.x) * dis;
            o.y = (a0.y + a1.y + a2.y + a3.y) * dis;
            o.z = (a0.z + a1.z + a2.z + a3.z) * dis;
            o.w = (a0.w + a1.w + a2.w + a3.w) * dis;
            ((float4*)t1)[(size_t)i * 16 + gl] = o;
        }
    }
}

// dense per-node dual GEMM: z2q = fp8(64 * (ReLU(gs*(t1@W1)+bias1)*dinv) @ w2l2)
// t row read via global broadcast (all lanes same addr); h staged bf16 in LDS;
// GEMM2 half-split across wave halves + shfl_xor combine. ~6 LDS ops/row.
__global__ __launch_bounds__(256, 2) void k_z(const float* __restrict__ t1,
                                              const int4* __restrict__ meta,
                                              const float* __restrict__ W1, const float* __restrict__ b1,
                                              const float* __restrict__ gamma, const float* __restrict__ beta,
                                              const float* __restrict__ w2l2, unsigned char* __restrict__ z2q, int N) {
    __shared__ __align__(16) unsigned short hb[4][F];  // bf16 h row per wave
    int tid = threadIdx.x, wave = tid >> 6, lane = tid & 63;
    int cc = lane & 31, khalf = lane >> 5;
    float gs = gamma[lane] * BN_INV;
    float bias1 = fmaf(b1[lane], gs, beta[lane]);
    float w1reg[F];
#pragma unroll
    for (int k = 0; k < F; k++) w1reg[k] = W1[k * F + lane] * gs;
    float w2reg[32];
#pragma unroll
    for (int j = 0; j < 32; j++) w2reg[j] = w2l2[(khalf * 32 + j) * OUTF + cc];

    for (int r = blockIdx.x * 4 + wave; r < N; r += gridDim.x * 4) {
        float di = __int_as_float(meta[r].z);
        const float4* trow = (const float4*)(t1 + (size_t)r * F);
        float o = bias1;
#pragma unroll
        for (int k4 = 0; k4 < 16; k4++) {
            float4 tv = trow[k4];  // all lanes same addr -> single 16B fetch
            o = fmaf(tv.x, w1reg[4 * k4 + 0], o);
            o = fmaf(tv.y, w1reg[4 * k4 + 1], o);
            o = fmaf(tv.z, w1reg[4 * k4 + 2], o);
            o = fmaf(tv.w, w1reg[4 * k4 + 3], o);
        }
        hb[wave][lane] = f2bf(fmaxf(o, 0.0f) * di);  // h (bf16)
        // GEMM2: each wave-half reduces its 32-k half
        float z = 0.0f;
        const uint4* h4 = (const uint4*)&hb[wave][khalf * 32];
#pragma unroll
        for (int q = 0; q < 4; q++) {
            uint4 hv = h4[q];  // 8 bf16
            z = fmaf(bf2f((unsigned short)hv.x), w2reg[8 * q + 0], z);
            z = fmaf(bf2f((unsigned short)(hv.x >> 16)), w2reg[8 * q + 1], z);
            z = fmaf(bf2f((unsigned short)hv.y), w2reg[8 * q + 2], z);
            z = fmaf(bf2f((unsigned short)(hv.y >> 16)), w2reg[8 * q + 3], z);
            z = fmaf(bf2f((unsigned short)hv.z), w2reg[8 * q + 4], z);
            z = fmaf(bf2f((unsigned short)(hv.z >> 16)), w2reg[8 * q + 5], z);
            z = fmaf(bf2f((unsigned short)hv.w), w2reg[8 * q + 6], z);
            z = fmaf(bf2f((unsigned short)(hv.w >> 16)), w2reg[8 * q + 7], z);
        }
        z += __shfl_xor(z, 32, 64);  // combine halves (same cc)
        if (lane < 32) z2q[(size_t)r * OUTF + cc] = fp8enc1(z * ESC_Z);
    }
}

// conv2: gather of fp8 z2q (32 B rows, L2-resident). wave = 8 nodes x 8 lanes x 4ch.
// vbuf[24] dword burst + sched_barrier; logits bf16; fused softmax/entropy head.
__global__ __launch_bounds__(256, 4) void k_conv2agg(const unsigned* __restrict__ z2q,
                                                     const int4* __restrict__ meta,
                                                     const int* __restrict__ eidx, const float* __restrict__ b2l2,
                                                     unsigned short* __restrict__ logits_bf, float* __restrict__ wraw,
                                                     unsigned* __restrict__ redmm, int N, int Em1) {
    __shared__ float smn[4], smx[4];
    int tid = threadIdx.x, wave = tid >> 6, lane = tid & 63;
    int g = lane >> 3, gl = lane & 7, gbase = lane & 56;
    float4 bvec = ((const float4*)b2l2)[gl];
    float mn = INFINITY, mx = -INFINITY;
    for (int i0 = (blockIdx.x * 4 + wave) * 8; i0 < N; i0 += gridDim.x * 32) {
        int i = i0 + g;
        int iclamp = min(i, N - 1);
        int4 m = meta[iclamp];
        int beg = m.x;
        int dcnt = (i < N) ? m.y : 0;
        float dis = __int_as_float(m.z) * IESC_Z;
        int ss0 = eidx[min(beg + gl, Em1)];
        int ss1 = eidx[min(beg + 8 + gl, Em1)];
        int ss2 = eidx[min(beg + 16 + gl, Em1)];
        unsigned selfv = z2q[(size_t)iclamp * 8 + gl];
        unsigned vbuf[24];
#pragma unroll
        for (int k = 0; k < 24; k++) {
            int sv = __shfl((k < 8) ? ss0 : (k < 16) ? ss1 : ss2, gbase + (k & 7), 64);
            sv = (k < dcnt) ? sv : iclamp;  // invalid slot -> own row (hot line)
            vbuf[k] = z2q[(size_t)sv * 8 + gl];
        }
        __builtin_amdgcn_sched_barrier(0);  // pin: full burst before first use
        float4 a0 = fp8x4(selfv);
        if (i >= N) a0 = make_float4(0.f, 0.f, 0.f, 0.f);
        float4 a1 = make_float4(0.f, 0.f, 0.f, 0.f), a2 = a1, a3 = a1;
#pragma unroll
        for (int k = 0; k < 24; k++) {
            if (k < dcnt) {
                float4 v = fp8x4(vbuf[k]);
                float4* a = (k & 3) == 0 ? &a0 : (k & 3) == 1 ? &a1 : (k & 3) == 2 ? &a2 : &a3;
                a->x += v.x; a->y += v.y; a->z += v.z; a->w += v.w;
            }
        }
        for (int base = 24; base < dcnt; base += 8) {  // rare tail
            int j = base + gl;
            int ss = eidx[min(beg + j, Em1)];
            int cnt = min(dcnt - base, 8);
#pragma unroll
            for (int k = 0; k < 8; k++) {
                if (k < cnt) {
                    int sv = __shfl(ss, gbase + k, 64);
                    float4 v = fp8x4(z2q[(size_t)sv * 8 + gl]);
                    float4* a = (k & 3) == 0 ? &a0 : (k & 3) == 1 ? &a1 : (k & 3) == 2 ? &a2 : &a3;
                    a->x += v.x; a->y += v.y; a->z += v.z; a->w += v.w;
                }
            }
        }
        float4 lg;
        lg.x = fmaf(a0.x + a1.x + a2.x + a3.x, dis, bvec.x);
        lg.y = fmaf(a0.y + a1.y + a2.y + a3.y, dis, bvec.y);
        lg.z = fmaf(a0.z + a1.z + a2.z + a3.z, dis, bvec.z);
        lg.w = fmaf(a0.w + a1.w + a2.w + a3.w, dis, bvec.w);
        if (i < N) {
            ushort4 ob;
            ob.x = f2bf(lg.x); ob.y = f2bf(lg.y); ob.z = f2bf(lg.z); ob.w = f2bf(lg.w);
            ((ushort4*)(logits_bf + (size_t)i * OUTF))[gl] = ob;
        }
        // softmax + entropy over 32 logits spread across 8 lanes x 4
        float m4 = fmaxf(fmaxf(lg.x, lg.y), fmaxf(lg.z, lg.w));
        for (int off = 4; off > 0; off >>= 1) m4 = fmaxf(m4, __shfl_xor(m4, off, 8));
        float p0 = expf(lg.x - m4), p1 = expf(lg.y - m4), p2 = expf(lg.z - m4), p3 = expf(lg.w - m4);
        float s4 = p0 + p1 + p2 + p3;
        for (int off = 4; off > 0; off >>= 1) s4 += __shfl_xor(s4, off, 8);
        float inv = 1.0f / s4;
        float t0 = p0 * inv, t1v = p1 * inv, t2v = p2 * inv, t3 = p3 * inv;
        float e4 = t0 * logf(t0 + 1e-9f) + t1v * logf(t1v + 1e-9f) + t2v * logf(t2v + 1e-9f) + t3 * logf(t3 + 1e-9f);
        for (int off = 4; off > 0; off >>= 1) e4 += __shfl_xor(e4, off, 8);
        float w = 1.0f / (-e4 + 1e-10f);
        if (i < N) {
            if (gl == 0) wraw[i] = w;
            mn = fminf(mn, w);
            mx = fmaxf(mx, w);
        }
    }
    for (int off = 32; off > 0; off >>= 1) {
        mn = fminf(mn, __shfl_xor(mn, off, 64));
        mx = fmaxf(mx, __shfl_xor(mx, off, 64));
    }
    if (lane == 0) { smn[wave] = mn; smx[wave] = mx; }
    __syncthreads();
    if (tid == 0) {
        float a = fminf(fminf(smn[0], smn[1]), fminf(smn[2], smn[3]));
        float b = fmaxf(fmaxf(smx[0], smx[1]), fmaxf(smx[2], smx[3]));
        atomicMin(&redmm[33], fenc(a));
        atomicMax(&redmm[34], fenc(b));
    }
}

__global__ __launch_bounds__(256) void k_weight(const unsigned short* __restrict__ logits_bf,
                                                const float* __restrict__ wraw,
                                                float* __restrict__ red, int N) {
    const unsigned* mm = (const unsigned*)red;
    float mn = fdec(mm[33]), mx = fdec(mm[34]);
    float inv = 1.0f / (mx - mn);
    int c = threadIdx.x & 31;
    int g = threadIdx.x >> 5;  // 8 row-groups
    float acc = 0.0f, es = 0.0f;
    for (int r = blockIdx.x * 8 + g; r < N; r += gridDim.x * 8) {
        float e = expf((wraw[r] - mn) * inv);
        acc += e * bf2f(logits_bf[(size_t)r * OUTF + c]);
        if (c == 0) es += e;
    }
    __shared__ float sa[8][OUTF];
    __shared__ float se[8];
    sa[g][c] = acc;
    if (c == 0) se[g] = es;
    __syncthreads();
    if (g == 0) {
        float t = sa[0][c];
#pragma unroll
        for (int i = 1; i < 8; i++) t += sa[i][c];
        unsafeAtomicAdd(&red[c], t);
        if (c == 0) {
            float u = 0.0f;
#pragma unroll
            for (int i = 0; i < 8; i++) u += se[i];
            unsafeAtomicAdd(&red[32], u);
        }
    }
}

__global__ void k_final(const float* __restrict__ red, const float* __restrict__ w3,
                        const float* __restrict__ b3, float* __restrict__ out) {
    int j = threadIdx.x;  // 64 threads
    float s = red[32];
    float o = b3[j];
#pragma unroll
    for (int cc = 0; cc < OUTF; cc++) o += (red[cc] / s) * w3[cc * F + j];
    out[j] = o;
}

extern "C" void kernel_launch(void* const* d_in, const int* in_sizes, int n_in,
                              void* d_out, int out_size, void* d_ws, size_t ws_size,
                              hipStream_t stream) {
    const float* x     = (const float*)d_in[0];
    const int*   ei    = (const int*)d_in[1];
    const float* W1    = (const float*)d_in[2];
    const float* b1    = (const float*)d_in[3];
    const float* gamma = (const float*)d_in[4];
    const float* beta  = (const float*)d_in[5];
    const float* W2    = (const float*)d_in[6];
    const float* b2    = (const float*)d_in[7];
    const float* l2w   = (const float*)d_in[8];
    const float* l2b   = (const float*)d_in[9];
    const float* l3w   = (const float*)d_in[10];
    const float* l3b   = (const float*)d_in[11];

    int N = in_sizes[0] / F;
    int E = in_sizes[1] / 2;
    const int* src = ei;
    const int* dst = ei + E;
    int NBK = (N + 255) >> 8;  // 391 buckets of 256 nodes (<=512 assumed)

    // workspace layout (16B-aligned chunks)
    char* p = (char*)d_ws;
    int* hist = (int*)p;                p += (size_t)PB * NBK * 4;
    int* btot = (int*)p;                p += 512 * 4;
    int* bbase = (int*)p;               p += 516 * 4;
    unsigned* bucketArr = (unsigned*)p; p += (size_t)E * 4;
    int4* meta = (int4*)p;              p += (size_t)N * 16;
    int* eidx = (int*)p;                p += (size_t)E * 4;
    float* red = (float*)p;             p += 64 * 4;
    float* w2l2 = (float*)p;            p += F * OUTF * 4;
    float* b2l2 = (float*)p;            p += OUTF * 4 + 32;
    unsigned* xq = (unsigned*)p;        p += (size_t)N * F;      // fp8, 64 B/row (aliased by z2q)
    float* t1 = (float*)p;              p += (size_t)N * F * 4;  // f32 (aliased by logits)
    float* wraw = (float*)p;            p += (size_t)N * 4;
    unsigned char* z2q = (unsigned char*)xq;       // xq dead after conv1agg; 32 B/row
    unsigned short* logits_bf = (unsigned short*)t1;  // t1 dead after k_z

    // setup + privatized counting-sort CSR build
    k_fuse<<<8, 256, 0, stream>>>(W2, b2, l2w, l2b, w2l2, b2l2, red);
    k_hist<<<PB, 256, 0, stream>>>(dst, hist, E, NBK);
    k_hscan1<<<NBK, PB, 0, stream>>>(hist, btot, NBK);
    k_hscan2<<<1, 512, 0, stream>>>(btot, bbase, NBK);
    k_place<<<PB, 256, 0, stream>>>(src, dst, hist, bbase, bucketArr, E, NBK);
    k_binsort<<<NBK, 256, 0, stream>>>(bucketArr, bbase, eidx, meta, N);
    k_prescale<<<(N * 16 + 255) / 256, 256, 0, stream>>>((const float4*)x, meta, xq, N * 16);

    // convs
    k_conv1agg<<<2048, 256, 0, stream>>>(xq, meta, eidx, t1, N, E - 1);
    k_z<<<1024, 256, 0, stream>>>(t1, meta, W1, b1, gamma, beta, w2l2, z2q, N);
    k_conv2agg<<<2048, 256, 0, stream>>>((const unsigned*)z2q, meta, eidx, b2l2, logits_bf, wraw, (unsigned*)red, N, E - 1);

    // pooling head
    k_weight<<<1024, 256, 0, stream>>>(logits_bf, wraw, red, N);
    k_final<<<1, 64, 0, stream>>>(red, l3w, l3b, (float*)d_out);
}

// Round 15
// 311.345 us; speedup vs baseline: 1.2820x; 1.0450x over previous
//
#include <hip/hip_runtime.h>
#include <hip/hip_bf16.h>
#include <hip/hip_fp8.h>
#include <math.h>

// GCN. CSR via block-privatized 2-pass counting sort; fp8-e4m3 gathered arrays.
// r15: r14 showed conv2agg FETCH 70->18MB with dur ~flat => request-path bound,
// not byte-bound. So: half the gather *instructions* (wider lanes: conv1 8
// lanes x 8B/row -> 8 nodes/wave; conv2 4 lanes x 8B/row -> 16 nodes/wave),
// exact-fit grids (no 2nd-iteration tail), prescale fused into binsort and
// fuse into hist (12 -> 10 launches).

#define F 64
#define OUTF 32
#define PB 128            // edge-partition blocks (privatized sort)
#define LEDGE 5632        // per-bucket LDS capacity (mean 4096)
#define BN_INV 0.9999950000374997f  // rsqrt(1 + 1e-5)
#define ESC_X 32.0f
#define IESC_X 0.03125f
#define ESC_Z 64.0f
#define IESC_Z 0.015625f

__device__ __forceinline__ unsigned fenc(float f) {
    unsigned u = __float_as_uint(f);
    return (u & 0x80000000u) ? ~u : (u | 0x80000000u);
}
__device__ __forceinline__ float fdec(unsigned e) {
    return (e & 0x80000000u) ? __uint_as_float(e & 0x7fffffffu) : __uint_as_float(~e);
}
__device__ __forceinline__ unsigned short f2bf(float f) {  // RNE
    unsigned u = __float_as_uint(f);
    return (unsigned short)((u + 0x7fffu + ((u >> 16) & 1u)) >> 16);
}
__device__ __forceinline__ float bf2f(unsigned short h) {
    return __uint_as_float((unsigned)h << 16);
}

#if __has_builtin(__builtin_amdgcn_cvt_f32_fp8) && __has_builtin(__builtin_amdgcn_cvt_pk_fp8_f32)
__device__ __forceinline__ float4 fp8x4(unsigned v) {
    return make_float4(__builtin_amdgcn_cvt_f32_fp8((int)v, 0),
                       __builtin_amdgcn_cvt_f32_fp8((int)v, 1),
                       __builtin_amdgcn_cvt_f32_fp8((int)v, 2),
                       __builtin_amdgcn_cvt_f32_fp8((int)v, 3));
}
__device__ __forceinline__ unsigned fp8pk4(float a, float b, float c, float d) {
    int r = __builtin_amdgcn_cvt_pk_fp8_f32(a, b, 0, false);
    r = __builtin_amdgcn_cvt_pk_fp8_f32(c, d, r, true);
    return (unsigned)r;
}
__device__ __forceinline__ unsigned char fp8enc1(float a) {
    return (unsigned char)(__builtin_amdgcn_cvt_pk_fp8_f32(a, a, 0, false) & 0xff);
}
#else
__device__ __forceinline__ float fp8d1(unsigned char b) {
    __hip_fp8_e4m3 v; v.__x = (__hip_fp8_storage_t)b; return (float)v;
}
__device__ __forceinline__ float4 fp8x4(unsigned v) {
    return make_float4(fp8d1(v & 255u), fp8d1((v >> 8) & 255u), fp8d1((v >> 16) & 255u), fp8d1((v >> 24) & 255u));
}
__device__ __forceinline__ unsigned char fp8enc1(float a) {
    return (unsigned char)__hip_fp8_e4m3(a).__x;
}
__device__ __forceinline__ unsigned fp8pk4(float a, float b, float c, float d) {
    return (unsigned)fp8enc1(a) | ((unsigned)fp8enc1(b) << 8) | ((unsigned)fp8enc1(c) << 16) | ((unsigned)fp8enc1(d) << 24);
}
#endif

// red layout: [0..31] acc_c, [32] esum, [33] min-enc(uint), [34] max-enc(uint)

// blocks 0..PB-1: histogram; blocks PB..PB+7: head-weight fusion + red init
__global__ __launch_bounds__(256) void k_hist(const int* __restrict__ dst, int* __restrict__ hist,
                                              int E, int NBK,
                                              const float* __restrict__ W2, const float* __restrict__ b2,
                                              const float* __restrict__ l2w, const float* __restrict__ l2b,
                                              float* __restrict__ w2l2, float* __restrict__ b2l2,
                                              float* __restrict__ red) {
    __shared__ int lh[512];
    int t = threadIdx.x, blk = blockIdx.x;
    if (blk >= PB) {  // fuse part
        int tt = (blk - PB) * 256 + t;  // 0..2047
        int k = tt >> 5, cc = tt & 31;
        float o = 0.0f;
        for (int j = 0; j < F; j++) o += W2[k * F + j] * l2w[j * OUTF + cc];
        w2l2[k * OUTF + cc] = o;
        if (tt < OUTF) {
            float b = l2b[tt];
            for (int j = 0; j < F; j++) b += b2[j] * l2w[j * OUTF + tt];
            b2l2[tt] = b;
        }
        if (tt < 33) red[tt] = 0.0f;
        if (tt == 33) ((unsigned*)red)[33] = 0xFFFFFFFFu;
        if (tt == 34) ((unsigned*)red)[34] = 0u;
        return;
    }
    for (int b = t; b < NBK; b += 256) lh[b] = 0;
    __syncthreads();
    int chunk = (E + PB - 1) / PB;
    int beg = blk * chunk, end = min(beg + chunk, E);
    for (int e = beg + t; e < end; e += 256) atomicAdd(&lh[dst[e] >> 8], 1);
    __syncthreads();
    for (int b = t; b < NBK; b += 256) hist[blk * NBK + b] = lh[b];  // dense coalesced
}

// per-bucket exclusive scan across the PB blocks (one block per bucket)
__global__ __launch_bounds__(PB) void k_hscan1(int* __restrict__ hist, int* __restrict__ btot, int NBK) {
    __shared__ int s[PB];
    int b = blockIdx.x, t = threadIdx.x;
    int v = hist[t * NBK + b];
    s[t] = v;
    __syncthreads();
    for (int off = 1; off < PB; off <<= 1) {
        int u = (t >= off) ? s[t - off] : 0;
        __syncthreads();
        s[t] += u;
        __syncthreads();
    }
    hist[t * NBK + b] = s[t] - v;  // exclusive within bucket
    if (t == PB - 1) btot[b] = s[t];
}

// scan bucket totals -> bbase (1 block; NBK <= 512)
__global__ void k_hscan2(const int* __restrict__ btot, int* __restrict__ bbase, int NBK) {
    __shared__ int s[512];
    int t = threadIdx.x;
    int v = (t < NBK) ? btot[t] : 0;
    s[t] = v;
    __syncthreads();
    for (int off = 1; off < 512; off <<= 1) {
        int u = (t >= off) ? s[t - off] : 0;
        __syncthreads();
        s[t] += u;
        __syncthreads();
    }
    if (t < NBK) {
        bbase[t] = s[t] - v;
        if (t == NBK - 1) bbase[NBK] = s[t];
    }
}

// pass 2: private cursors in LDS (hist offset + bucket base); single-writer lines
__global__ __launch_bounds__(256) void k_place(const int* __restrict__ src, const int* __restrict__ dst,
                                               const int* __restrict__ hist, const int* __restrict__ bbase,
                                               unsigned* __restrict__ bucketArr, int E, int NBK) {
    __shared__ int cur[512];
    int t = threadIdx.x, blk = blockIdx.x;
    for (int b = t; b < NBK; b += 256) cur[b] = hist[blk * NBK + b] + bbase[b];
    __syncthreads();
    int chunk = (E + PB - 1) / PB;
    int beg = blk * chunk, end = min(beg + chunk, E);
    for (int e = beg + t; e < end; e += 256) {
        int d = dst[e], sidx = src[e];
        int p = atomicAdd(&cur[d >> 8], 1);
        bucketArr[p] = ((unsigned)sidx << 8) | (unsigned)(d & 255);
    }
}

// one block per bucket: LDS count -> scan -> place -> fused x-prescale.
// Emits CSR eidx + meta{beg,deg,dinv} + xq = fp8(x*dinv*32).
__global__ __launch_bounds__(256) void k_binsort(const unsigned* __restrict__ bucketArr,
                                                 const int* __restrict__ bbase,
                                                 int* __restrict__ eidx, int4* __restrict__ meta,
                                                 const float4* __restrict__ x4, unsigned* __restrict__ xq, int N) {
    __shared__ unsigned ledge[LEDGE];
    __shared__ int lcnt[256], lofs[256], lcur[256], lscan[256];
    __shared__ float ldinv[256];
    int b = blockIdx.x, t = threadIdx.x;
    int gb = bbase[b];
    int count = min(bbase[b + 1] - gb, LEDGE);
    for (int j = t; j < count; j += 256) ledge[j] = bucketArr[gb + j];
    lcnt[t] = 0;
    __syncthreads();
    for (int j = t; j < count; j += 256) atomicAdd(&lcnt[ledge[j] & 255u], 1);
    __syncthreads();
    int deg = lcnt[t];
    lscan[t] = deg;
    __syncthreads();
    for (int off = 1; off < 256; off <<= 1) {
        int u = (t >= off) ? lscan[t - off] : 0;
        __syncthreads();
        lscan[t] += u;
        __syncthreads();
    }
    lofs[t] = lscan[t] - deg;  // exclusive
    lcur[t] = 0;
    int node = (b << 8) + t;
    float di = rsqrtf((float)deg + 1.0f);
    ldinv[t] = di;
    if (node < N) meta[node] = make_int4(gb + lofs[t], deg, __float_as_int(di), 0);
    __syncthreads();
    for (int j = t; j < count; j += 256) {
        unsigned v = ledge[j];
        int loc = (int)(v & 255u);
        int p = atomicAdd(&lcur[loc], 1);
        eidx[gb + lofs[loc] + p] = (int)(v >> 8);  // single-writer 16KB window
    }
    // fused prescale for this bucket's 256 nodes (coalesced: 16 threads/node)
    for (int idx = t; idx < 256 * 16; idx += 256) {
        int nd = (b << 8) + (idx >> 4);
        if (nd < N) {
            float d2 = ldinv[idx >> 4] * ESC_X;
            float4 v = x4[(size_t)nd * 16 + (idx & 15)];
            xq[(size_t)nd * 16 + (idx & 15)] = fp8pk4(v.x * d2, v.y * d2, v.z * d2, v.w * d2);
        }
    }
}

// conv1: t1 = f32( dinv/32 * (sum_nbr xq[s] + xq[i]) ).
// wave = 8 nodes x 8 lanes x 8ch (uint2 = 8 fp8 per lane). Exact-fit grid: 1 batch/wave.
__global__ __launch_bounds__(256, 4) void k_conv1agg(const uint2* __restrict__ xq2,
                                                     const int4* __restrict__ meta,
                                                     const int* __restrict__ eidx,
                                                     float* __restrict__ t1, int N, int Em1) {
    int tid = threadIdx.x, wave = tid >> 6, lane = tid & 63;
    int g = lane >> 3, gl = lane & 7, gbase = lane & 56;
    int i = (blockIdx.x * 4 + wave) * 8 + g;
    int iclamp = min(i, N - 1);
    int4 m = meta[iclamp];
    int beg = m.x;
    int dcnt = (i < N) ? m.y : 0;
    float dis = __int_as_float(m.z) * IESC_X;
    int ss0 = eidx[min(beg + gl, Em1)];
    int ss1 = eidx[min(beg + 8 + gl, Em1)];
    int ss2 = eidx[min(beg + 16 + gl, Em1)];
    int ss3 = eidx[min(beg + 24 + gl, Em1)];
    uint2 selfv = xq2[(size_t)iclamp * 8 + gl];
    uint2 vbuf[32];
#pragma unroll
    for (int k = 0; k < 32; k++) {
        int sreg = (k < 8) ? ss0 : (k < 16) ? ss1 : (k < 24) ? ss2 : ss3;
        int sv = __shfl(sreg, gbase + (k & 7), 64);
        sv = (k < dcnt) ? sv : iclamp;  // invalid slot -> own row (hot line)
        vbuf[k] = xq2[(size_t)sv * 8 + gl];
    }
    __builtin_amdgcn_sched_barrier(0);  // pin: full burst before first use
    float4 aA0 = fp8x4(selfv.x), aB0 = fp8x4(selfv.y);
    float4 aA1 = make_float4(0.f, 0.f, 0.f, 0.f), aB1 = aA1;
#pragma unroll
    for (int k = 0; k < 32; k++) {
        if (k < dcnt) {
            float4 vA = fp8x4(vbuf[k].x), vB = fp8x4(vbuf[k].y);
            if (k & 1) {
                aA1.x += vA.x; aA1.y += vA.y; aA1.z += vA.z; aA1.w += vA.w;
                aB1.x += vB.x; aB1.y += vB.y; aB1.z += vB.z; aB1.w += vB.w;
            } else {
                aA0.x += vA.x; aA0.y += vA.y; aA0.z += vA.z; aA0.w += vA.w;
                aB0.x += vB.x; aB0.y += vB.y; aB0.z += vB.z; aB0.w += vB.w;
            }
        }
    }
    for (int base = 32; base < dcnt; base += 8) {  // rare tail
        int j = base + gl;
        int ss = eidx[min(beg + j, Em1)];
        int cnt = min(dcnt - base, 8);
#pragma unroll
        for (int k = 0; k < 8; k++) {
            if (k < cnt) {
                int sv = __shfl(ss, gbase + k, 64);
                uint2 v = xq2[(size_t)sv * 8 + gl];
                float4 vA = fp8x4(v.x), vB = fp8x4(v.y);
                aA0.x += vA.x; aA0.y += vA.y; aA0.z += vA.z; aA0.w += vA.w;
                aB0.x += vB.x; aB0.y += vB.y; aB0.z += vB.z; aB0.w += vB.w;
            }
        }
    }
    if (i < N) {
        float4 oA, oB;
        oA.x = (aA0.x + aA1.x) * dis; oA.y = (aA0.y + aA1.y) * dis;
        oA.z = (aA0.z + aA1.z) * dis; oA.w = (aA0.w + aA1.w) * dis;
        oB.x = (aB0.x + aB1.x) * dis; oB.y = (aB0.y + aB1.y) * dis;
        oB.z = (aB0.z + aB1.z) * dis; oB.w = (aB0.w + aB1.w) * dis;
        float4* out = (float4*)(t1 + (size_t)i * F + gl * 8);
        out[0] = oA;
        out[1] = oB;
    }
}

// dense per-node dual GEMM: z2q = fp8(64 * (ReLU(gs*(t1@W1)+bias1)*dinv) @ w2l2)
__global__ __launch_bounds__(256, 2) void k_z(const float* __restrict__ t1,
                                              const int4* __restrict__ meta,
                                              const float* __restrict__ W1, const float* __restrict__ b1,
                                              const float* __restrict__ gamma, const float* __restrict__ beta,
                                              const float* __restrict__ w2l2, unsigned char* __restrict__ z2q, int N) {
    __shared__ __align__(16) unsigned short hb[4][F];  // bf16 h row per wave
    int tid = threadIdx.x, wave = tid >> 6, lane = tid & 63;
    int cc = lane & 31, khalf = lane >> 5;
    float gs = gamma[lane] * BN_INV;
    float bias1 = fmaf(b1[lane], gs, beta[lane]);
    float w1reg[F];
#pragma unroll
    for (int k = 0; k < F; k++) w1reg[k] = W1[k * F + lane] * gs;
    float w2reg[32];
#pragma unroll
    for (int j = 0; j < 32; j++) w2reg[j] = w2l2[(khalf * 32 + j) * OUTF + cc];

    for (int r = blockIdx.x * 4 + wave; r < N; r += gridDim.x * 4) {
        float di = __int_as_float(meta[r].z);
        const float4* trow = (const float4*)(t1 + (size_t)r * F);
        float o = bias1;
#pragma unroll
        for (int k4 = 0; k4 < 16; k4++) {
            float4 tv = trow[k4];  // all lanes same addr -> single 16B fetch
            o = fmaf(tv.x, w1reg[4 * k4 + 0], o);
            o = fmaf(tv.y, w1reg[4 * k4 + 1], o);
            o = fmaf(tv.z, w1reg[4 * k4 + 2], o);
            o = fmaf(tv.w, w1reg[4 * k4 + 3], o);
        }
        hb[wave][lane] = f2bf(fmaxf(o, 0.0f) * di);  // h (bf16)
        float z = 0.0f;
        const uint4* h4 = (const uint4*)&hb[wave][khalf * 32];
#pragma unroll
        for (int q = 0; q < 4; q++) {
            uint4 hv = h4[q];  // 8 bf16
            z = fmaf(bf2f((unsigned short)hv.x), w2reg[8 * q + 0], z);
            z = fmaf(bf2f((unsigned short)(hv.x >> 16)), w2reg[8 * q + 1], z);
            z = fmaf(bf2f((unsigned short)hv.y), w2reg[8 * q + 2], z);
            z = fmaf(bf2f((unsigned short)(hv.y >> 16)), w2reg[8 * q + 3], z);
            z = fmaf(bf2f((unsigned short)hv.z), w2reg[8 * q + 4], z);
            z = fmaf(bf2f((unsigned short)(hv.z >> 16)), w2reg[8 * q + 5], z);
            z = fmaf(bf2f((unsigned short)hv.w), w2reg[8 * q + 6], z);
            z = fmaf(bf2f((unsigned short)(hv.w >> 16)), w2reg[8 * q + 7], z);
        }
        z += __shfl_xor(z, 32, 64);  // combine halves (same cc)
        if (lane < 32) z2q[(size_t)r * OUTF + cc] = fp8enc1(z * ESC_Z);
    }
}

// conv2: gather of fp8 z2q (32 B rows, L2-resident). wave = 16 nodes x 4 lanes x 8ch.
// vbuf[24] uint2 burst + sched_barrier; logits bf16; fused softmax/entropy head.
__global__ __launch_bounds__(256, 4) void k_conv2agg(const uint2* __restrict__ z2q2,
                                                     const int4* __restrict__ meta,
                                                     const int* __restrict__ eidx, const float* __restrict__ b2l2,
                                                     unsigned short* __restrict__ logits_bf, float* __restrict__ wraw,
                                                     unsigned* __restrict__ redmm, int N, int Em1) {
    __shared__ float smn[4], smx[4];
    int tid = threadIdx.x, wave = tid >> 6, lane = tid & 63;
    int g = lane >> 2, gl = lane & 3, gbase = lane & 60;
    float4 bvA = ((const float4*)b2l2)[gl * 2];
    float4 bvB = ((const float4*)b2l2)[gl * 2 + 1];
    int i = (blockIdx.x * 4 + wave) * 16 + g;
    int iclamp = min(i, N - 1);
    int4 m = meta[iclamp];
    int beg = m.x;
    int dcnt = (i < N) ? m.y : 0;
    float dis = __int_as_float(m.z) * IESC_Z;
    int ss0 = eidx[min(beg + gl, Em1)];
    int ss1 = eidx[min(beg + 4 + gl, Em1)];
    int ss2 = eidx[min(beg + 8 + gl, Em1)];
    int ss3 = eidx[min(beg + 12 + gl, Em1)];
    int ss4 = eidx[min(beg + 16 + gl, Em1)];
    int ss5 = eidx[min(beg + 20 + gl, Em1)];
    uint2 selfv = z2q2[(size_t)iclamp * 4 + gl];
    uint2 vbuf[24];
#pragma unroll
    for (int k = 0; k < 24; k++) {
        int sreg = (k < 4) ? ss0 : (k < 8) ? ss1 : (k < 12) ? ss2 : (k < 16) ? ss3 : (k < 20) ? ss4 : ss5;
        int sv = __shfl(sreg, gbase + (k & 3), 64);
        sv = (k < dcnt) ? sv : iclamp;  // invalid slot -> own row (hot line)
        vbuf[k] = z2q2[(size_t)sv * 4 + gl];
    }
    __builtin_amdgcn_sched_barrier(0);  // pin: full burst before first use
    float4 aA0 = fp8x4(selfv.x), aB0 = fp8x4(selfv.y);
    if (i >= N) { aA0 = make_float4(0.f, 0.f, 0.f, 0.f); aB0 = aA0; }
    float4 aA1 = make_float4(0.f, 0.f, 0.f, 0.f), aB1 = aA1;
#pragma unroll
    for (int k = 0; k < 24; k++) {
        if (k < dcnt) {
            float4 vA = fp8x4(vbuf[k].x), vB = fp8x4(vbuf[k].y);
            if (k & 1) {
                aA1.x += vA.x; aA1.y += vA.y; aA1.z += vA.z; aA1.w += vA.w;
                aB1.x += vB.x; aB1.y += vB.y; aB1.z += vB.z; aB1.w += vB.w;
            } else {
                aA0.x += vA.x; aA0.y += vA.y; aA0.z += vA.z; aA0.w += vA.w;
                aB0.x += vB.x; aB0.y += vB.y; aB0.z += vB.z; aB0.w += vB.w;
            }
        }
    }
    for (int base = 24; base < dcnt; base += 4) {  // rare tail
        int j = base + gl;
        int ss = eidx[min(beg + j, Em1)];
        int cnt = min(dcnt - base, 4);
#pragma unroll
        for (int k = 0; k < 4; k++) {
            if (k < cnt) {
                int sv = __shfl(ss, gbase + k, 64);
                uint2 v = z2q2[(size_t)sv * 4 + gl];
                float4 vA = fp8x4(v.x), vB = fp8x4(v.y);
                aA0.x += vA.x; aA0.y += vA.y; aA0.z += vA.z; aA0.w += vA.w;
                aB0.x += vB.x; aB0.y += vB.y; aB0.z += vB.z; aB0.w += vB.w;
            }
        }
    }
    float4 lgA, lgB;
    lgA.x = fmaf(aA0.x + aA1.x, dis, bvA.x);
    lgA.y = fmaf(aA0.y + aA1.y, dis, bvA.y);
    lgA.z = fmaf(aA0.z + aA1.z, dis, bvA.z);
    lgA.w = fmaf(aA0.w + aA1.w, dis, bvA.w);
    lgB.x = fmaf(aB0.x + aB1.x, dis, bvB.x);
    lgB.y = fmaf(aB0.y + aB1.y, dis, bvB.y);
    lgB.z = fmaf(aB0.z + aB1.z, dis, bvB.z);
    lgB.w = fmaf(aB0.w + aB1.w, dis, bvB.w);
    if (i < N) {
        uint4 ob;
        ob.x = (unsigned)f2bf(lgA.x) | ((unsigned)f2bf(lgA.y) << 16);
        ob.y = (unsigned)f2bf(lgA.z) | ((unsigned)f2bf(lgA.w) << 16);
        ob.z = (unsigned)f2bf(lgB.x) | ((unsigned)f2bf(lgB.y) << 16);
        ob.w = (unsigned)f2bf(lgB.z) | ((unsigned)f2bf(lgB.w) << 16);
        *(uint4*)(logits_bf + (size_t)i * OUTF + gl * 8) = ob;
    }
    // softmax + entropy over 32 logits spread across 4 lanes x 8
    float m8 = fmaxf(fmaxf(fmaxf(lgA.x, lgA.y), fmaxf(lgA.z, lgA.w)),
                     fmaxf(fmaxf(lgB.x, lgB.y), fmaxf(lgB.z, lgB.w)));
    for (int off = 2; off > 0; off >>= 1) m8 = fmaxf(m8, __shfl_xor(m8, off, 4));
    float p0 = expf(lgA.x - m8), p1 = expf(lgA.y - m8), p2 = expf(lgA.z - m8), p3 = expf(lgA.w - m8);
    float p4 = expf(lgB.x - m8), p5 = expf(lgB.y - m8), p6 = expf(lgB.z - m8), p7 = expf(lgB.w - m8);
    float s8 = p0 + p1 + p2 + p3 + p4 + p5 + p6 + p7;
    for (int off = 2; off > 0; off >>= 1) s8 += __shfl_xor(s8, off, 4);
    float inv = 1.0f / s8;
    float t0 = p0 * inv, t1v = p1 * inv, t2v = p2 * inv, t3 = p3 * inv;
    float t4 = p4 * inv, t5 = p5 * inv, t6 = p6 * inv, t7 = p7 * inv;
    float e8 = t0 * logf(t0 + 1e-9f) + t1v * logf(t1v + 1e-9f) + t2v * logf(t2v + 1e-9f) + t3 * logf(t3 + 1e-9f) +
               t4 * logf(t4 + 1e-9f) + t5 * logf(t5 + 1e-9f) + t6 * logf(t6 + 1e-9f) + t7 * logf(t7 + 1e-9f);
    for (int off = 2; off > 0; off >>= 1) e8 += __shfl_xor(e8, off, 4);
    float w = 1.0f / (-e8 + 1e-10f);
    float mn = INFINITY, mx = -INFINITY;
    if (i < N) {
        if (gl == 0) wraw[i] = w;
        mn = w;
        mx = w;
    }
    for (int off = 32; off > 0; off >>= 1) {
        mn = fminf(mn, __shfl_xor(mn, off, 64));
        mx = fmaxf(mx, __shfl_xor(mx, off, 64));
    }
    if (lane == 0) { smn[wave] = mn; smx[wave] = mx; }
    __syncthreads();
    if (tid == 0) {
        float a = fminf(fminf(smn[0], smn[1]), fminf(smn[2], smn[3]));
        float b = fmaxf(fmaxf(smx[0], smx[1]), fmaxf(smx[2], smx[3]));
        atomicMin(&redmm[33], fenc(a));
        atomicMax(&redmm[34], fenc(b));
    }
}

__global__ __launch_bounds__(256) void k_weight(const unsigned short* __restrict__ logits_bf,
                                                const float* __restrict__ wraw,
                                                float* __restrict__ red, int N) {
    const unsigned* mm = (const unsigned*)red;
    float mn = fdec(mm[33]), mx = fdec(mm[34]);
    float inv = 1.0f / (mx - mn);
    int c = threadIdx.x & 31;
    int g = threadIdx.x >> 5;  // 8 row-groups
    float acc = 0.0f, es = 0.0f;
    for (int r = blockIdx.x * 8 + g; r < N; r += gridDim.x * 8) {
        float e = expf((wraw[r] - mn) * inv);
        acc += e * bf2f(logits_bf[(size_t)r * OUTF + c]);
        if (c == 0) es += e;
    }
    __shared__ float sa[8][OUTF];
    __shared__ float se[8];
    sa[g][c] = acc;
    if (c == 0) se[g] = es;
    __syncthreads();
    if (g == 0) {
        float t = sa[0][c];
#pragma unroll
        for (int i = 1; i < 8; i++) t += sa[i][c];
        unsafeAtomicAdd(&red[c], t);
        if (c == 0) {
            float u = 0.0f;
#pragma unroll
            for (int i = 0; i < 8; i++) u += se[i];
            unsafeAtomicAdd(&red[32], u);
        }
    }
}

__global__ void k_final(const float* __restrict__ red, const float* __restrict__ w3,
                        const float* __restrict__ b3, float* __restrict__ out) {
    int j = threadIdx.x;  // 64 threads
    float s = red[32];
    float o = b3[j];
#pragma unroll
    for (int cc = 0; cc < OUTF; cc++) o += (red[cc] / s) * w3[cc * F + j];
    out[j] = o;
}

extern "C" void kernel_launch(void* const* d_in, const int* in_sizes, int n_in,
                              void* d_out, int out_size, void* d_ws, size_t ws_size,
                              hipStream_t stream) {
    const float* x     = (const float*)d_in[0];
    const int*   ei    = (const int*)d_in[1];
    const float* W1    = (const float*)d_in[2];
    const float* b1    = (const float*)d_in[3];
    const float* gamma = (const float*)d_in[4];
    const float* beta  = (const float*)d_in[5];
    const float* W2    = (const float*)d_in[6];
    const float* b2    = (const float*)d_in[7];
    const float* l2w   = (const float*)d_in[8];
    const float* l2b   = (const float*)d_in[9];
    const float* l3w   = (const float*)d_in[10];
    const float* l3b   = (const float*)d_in[11];

    int N = in_sizes[0] / F;
    int E = in_sizes[1] / 2;
    const int* src = ei;
    const int* dst = ei + E;
    int NBK = (N + 255) >> 8;  // 391 buckets of 256 nodes (<=512 assumed)

    // workspace layout (16B-aligned chunks)
    char* p = (char*)d_ws;
    int* hist = (int*)p;                p += (size_t)PB * NBK * 4;
    int* btot = (int*)p;                p += 512 * 4;
    int* bbase = (int*)p;               p += 516 * 4;
    unsigned* bucketArr = (unsigned*)p; p += (size_t)E * 4;
    int4* meta = (int4*)p;              p += (size_t)N * 16;
    int* eidx = (int*)p;                p += (size_t)E * 4;
    float* red = (float*)p;             p += 64 * 4;
    float* w2l2 = (float*)p;            p += F * OUTF * 4;
    float* b2l2 = (float*)p;            p += OUTF * 4 + 32;
    unsigned* xq = (unsigned*)p;        p += (size_t)N * F;      // fp8, 64 B/row (aliased by z2q)
    float* t1 = (float*)p;              p += (size_t)N * F * 4;  // f32 (aliased by logits)
    float* wraw = (float*)p;            p += (size_t)N * 4;
    unsigned char* z2q = (unsigned char*)xq;       // xq dead after conv1agg; 32 B/row
    unsigned short* logits_bf = (unsigned short*)t1;  // t1 dead after k_z

    // setup + privatized counting-sort CSR build (fuse merged into hist grid)
    k_hist<<<PB + 8, 256, 0, stream>>>(dst, hist, E, NBK, W2, b2, l2w, l2b, w2l2, b2l2, red);
    k_hscan1<<<NBK, PB, 0, stream>>>(hist, btot, NBK);
    k_hscan2<<<1, 512, 0, stream>>>(btot, bbase, NBK);
    k_place<<<PB, 256, 0, stream>>>(src, dst, hist, bbase, bucketArr, E, NBK);
    k_binsort<<<NBK, 256, 0, stream>>>(bucketArr, bbase, eidx, meta, (const float4*)x, xq, N);

    // convs (exact-fit grids: one node-batch per wave)
    k_conv1agg<<<(N + 31) / 32, 256, 0, stream>>>((const uint2*)xq, meta, eidx, t1, N, E - 1);
    k_z<<<1024, 256, 0, stream>>>(t1, meta, W1, b1, gamma, beta, w2l2, z2q, N);
    k_conv2agg<<<(N + 63) / 64, 256, 0, stream>>>((const uint2*)z2q, meta, eidx, b2l2, logits_bf, wraw, (unsigned*)red, N, E - 1);

    // pooling head
    k_weight<<<1024, 256, 0, stream>>>(logits_bf, wraw, red, N);
    k_final<<<1, 64, 0, stream>>>(red, l3w, l3b, (float*)d_out);
}